// Round 1
// baseline (3457.581 us; speedup 1.0000x reference)
//
#include <hip/hip_runtime.h>
#include <math.h>

namespace {
constexpr int cB = 16, cN = 8192, cC = 64, cK = 128, cR = 4, cNL = 4;
constexpr float kTwoPi = 6.28318530717958647692f;

// workspace layout (float offsets)
constexpr size_t OFF_HA   = 0;
constexpr size_t OFF_HB   = (size_t)cB * cC * cN;            // 8388608
constexpr size_t OFF_PACK = OFF_HB * 2;                      // 16777216 (B*N float4)
constexpr size_t OFF_XC   = OFF_PACK + (size_t)cB * cN * 4;  // 17301504
constexpr size_t OFF_XS   = OFF_XC + (size_t)cB * cC * cK;
constexpr size_t OFF_X0   = OFF_XS + (size_t)cB * cC * cK;
constexpr size_t OFF_FCT  = OFF_X0 + (size_t)cB * cC;
constexpr size_t OFF_FST  = OFF_FCT + (size_t)cB * cK * cC;
constexpr size_t OFF_F0   = OFF_FST + (size_t)cB * cK * cC;
// total = OFF_F0 + cB*cC = 17827840 floats = 71.3 MB

__device__ __forceinline__ float gelu_f(float x) {
  return 0.5f * x * (1.0f + erff(x * 0.7071067811865475244f));
}
}  // namespace

// --- prep: fc0 matmul into (B,C,N) layout + pack grid/weights/mask + zero accumulators
__global__ void __launch_bounds__(256) k_prep(const float* __restrict__ x,
                                              const float* __restrict__ fc0_w,
                                              const float* __restrict__ fc0_b,
                                              float* __restrict__ ws) {
  int t = blockIdx.x * 256 + threadIdx.x;  // 0..B*N-1
  int b = t >> 13;
  int n = t & (cN - 1);
  const float* xp = x + (size_t)t * 7;
  float f0 = xp[0], f1 = xp[1], f2 = xp[2];
  float gx = xp[3], gy = xp[4], w = xp[5], m = xp[6];
  float4* pack = (float4*)(ws + OFF_PACK);
  pack[t] = make_float4(gx, gy, w * (float)cN * m, m);  // a = mask*weights*size
  float* h = ws + OFF_HA + (size_t)b * cC * cN + n;
#pragma unroll
  for (int c = 0; c < cC; c++) {
    float v = fc0_b[c] + f0 * fc0_w[c] + f1 * fc0_w[cC + c] + f2 * fc0_w[2 * cC + c];
    h[(size_t)c * cN] = v;
  }
  // zero Xc, Xs, X0 (contiguous region) for layer 0
  float* acc = ws + OFF_XC;
  for (int i = t; i < 2 * cB * cC * cK + cB * cC; i += cB * cN) acc[i] = 0.0f;
}

// --- forward transform: Xc[b,c,k] = sum_n h*a*cos, Xs = sum_n h*a*sin, X0 = sum_n h*a
__global__ void __launch_bounds__(256) k_forward(const float* __restrict__ h,
                                                 const float* __restrict__ ws,
                                                 float* __restrict__ Xc,
                                                 float* __restrict__ Xs,
                                                 float* __restrict__ X0) {
  constexpr int S_CHUNK = 512;
  constexpr int TN = 32;
  int b = blockIdx.y;
  int n_base = blockIdx.x * S_CHUNK;
  int tid = threadIdx.x;
  int tc = tid >> 4;  // 0..15 -> c0 = tc*4
  int tk = tid & 15;  // 0..15 -> k0 = tk*8
  __shared__ __align__(16) float hs[TN * 68];    // [nn][c], pad 68
  __shared__ __align__(16) float cw[TN * 132];   // [nn][k], pad 132
  __shared__ __align__(16) float sw[TN * 132];
  float accC[4][8], accS[4][8], acc0[4];
#pragma unroll
  for (int j = 0; j < 4; j++) {
    acc0[j] = 0.0f;
#pragma unroll
    for (int q = 0; q < 8; q++) { accC[j][q] = 0.0f; accS[j][q] = 0.0f; }
  }
  const float4* pack = (const float4*)(ws + OFF_PACK) + (size_t)b * cN;
  const float* hb = h + (size_t)b * cC * cN;
  int nn_l = tid & 31;
  int kc_l = tid >> 5;  // 0..7
  for (int t0 = 0; t0 < S_CHUNK; t0 += TN) {
    int n0 = n_base + t0;
    float4 p = pack[n0 + nn_l];
    // stage h*a (a folded into h so X0 = sum hs)
#pragma unroll
    for (int i = 0; i < 8; i++) {
      int c = kc_l + i * 8;
      hs[nn_l * 68 + c] = hb[(size_t)c * cN + n0 + nn_l] * p.z;
    }
    // stage cos/sin
#pragma unroll
    for (int i = 0; i < 16; i++) {
      int k = kc_l + i * 8;
      int kx = k >> 3, ky = k & 7;
      float ang = p.x * (kTwoPi * (float)kx) + p.y * (kTwoPi * (float)ky);
      float sv, cv;
      sincosf(ang, &sv, &cv);
      cw[nn_l * 132 + k] = cv;
      sw[nn_l * 132 + k] = sv;
    }
    __syncthreads();
#pragma unroll 4
    for (int nn = 0; nn < TN; nn++) {
      float4 hv = *(const float4*)&hs[nn * 68 + tc * 4];
      float4 ca = *(const float4*)&cw[nn * 132 + tk * 8];
      float4 cb = *(const float4*)&cw[nn * 132 + tk * 8 + 4];
      float4 sa = *(const float4*)&sw[nn * 132 + tk * 8];
      float4 sb = *(const float4*)&sw[nn * 132 + tk * 8 + 4];
      float hj[4] = {hv.x, hv.y, hv.z, hv.w};
      float cc[8] = {ca.x, ca.y, ca.z, ca.w, cb.x, cb.y, cb.z, cb.w};
      float ss[8] = {sa.x, sa.y, sa.z, sa.w, sb.x, sb.y, sb.z, sb.w};
#pragma unroll
      for (int j = 0; j < 4; j++) {
#pragma unroll
        for (int q = 0; q < 8; q++) {
          accC[j][q] += hj[j] * cc[q];
          accS[j][q] += hj[j] * ss[q];
        }
      }
      if (tk == 0) {
#pragma unroll
        for (int j = 0; j < 4; j++) acc0[j] += hj[j];
      }
    }
    __syncthreads();
  }
  float* xcb = Xc + (size_t)b * cC * cK;
  float* xsb = Xs + (size_t)b * cC * cK;
#pragma unroll
  for (int j = 0; j < 4; j++) {
    int c = tc * 4 + j;
#pragma unroll
    for (int q = 0; q < 8; q++) {
      int k = tk * 8 + q;
      atomicAdd(&xcb[c * cK + k], accC[j][q]);
      atomicAdd(&xsb[c * cK + k], accS[j][q]);
    }
  }
  if (tk == 0) {
#pragma unroll
    for (int j = 0; j < 4; j++) atomicAdd(&X0[b * cC + tc * 4 + j], acc0[j]);
  }
}

// --- low-rank mixing per (b,k); also zeroes Xc/Xs/X0 for next layer
__global__ void k_lowrank(float* __restrict__ Xc, float* __restrict__ Xs,
                          float* __restrict__ X0, const float* __restrict__ wc1,
                          const float* __restrict__ wc2, const float* __restrict__ ws1,
                          const float* __restrict__ ws2, const float* __restrict__ w01,
                          const float* __restrict__ w02, float* __restrict__ FcT,
                          float* __restrict__ FsT, float* __restrict__ F0, int layer) {
  int b = blockIdx.x;
  int k = threadIdx.x;
  const float* c1 = wc1 + (size_t)layer * cC * cR * cK;
  const float* s1 = ws1 + (size_t)layer * cC * cR * cK;
  const float* c2 = wc2 + (size_t)layer * cR * cC * cK;
  const float* s2 = ws2 + (size_t)layer * cR * cC * cK;
  float A1[cR] = {}, A2[cR] = {}, B1[cR] = {}, B2[cR] = {};
  float* xcb = Xc + (size_t)b * cC * cK;
  float* xsb = Xs + (size_t)b * cC * cK;
  for (int i = 0; i < cC; i++) {
    size_t idx = (size_t)i * cK + k;
    float xcv = xcb[idx]; xcb[idx] = 0.0f;
    float xsv = -xsb[idx]; xsb[idx] = 0.0f;  // x_s = -sum(h*a*sin)
#pragma unroll
    for (int r = 0; r < cR; r++) {
      float w1c = c1[((size_t)i * cR + r) * cK + k];
      float w1sv = s1[((size_t)i * cR + r) * cK + k];
      A1[r] += xcv * w1c;
      A2[r] += xcv * w1sv;
      B1[r] += xsv * w1c;
      B2[r] += xsv * w1sv;
    }
  }
  const float scale = 2.0f / (float)cN;  // inv_sqrt^2 * (2x from inverse transform)
  float* fct = FcT + ((size_t)b * cK + k) * cC;
  float* fst = FsT + ((size_t)b * cK + k) * cC;
  for (int o = 0; o < cC; o++) {
    float fc = 0.0f, fs = 0.0f;
#pragma unroll
    for (int r = 0; r < cR; r++) {
      float w2c = c2[((size_t)r * cC + o) * cK + k];
      float w2s = s2[((size_t)r * cC + o) * cK + k];
      fc += A1[r] * w2c - B2[r] * w2s;  // LR(x_c,c) - LR(x_s,s)
      fs += B1[r] * w2c + A2[r] * w2s;  // LR(x_s,c) + LR(x_c,s)
    }
    fct[o] = scale * fc;
    fst[o] = scale * fs;
  }
  if (k == 0) {
    float t[cR] = {};
    for (int i = 0; i < cC; i++) {
      float xv = X0[b * cC + i];
      X0[b * cC + i] = 0.0f;
#pragma unroll
      for (int r = 0; r < cR; r++) t[r] += xv * w01[((size_t)layer * cC + i) * cR + r];
    }
    for (int o = 0; o < cC; o++) {
      float f = 0.0f;
#pragma unroll
      for (int r = 0; r < cR; r++) f += t[r] * w02[((size_t)layer * cR + r) * cC + o];
      F0[b * cC + o] = f / (float)cN;
    }
  }
}

// --- inverse transform + conv + bias + gelu
__global__ void __launch_bounds__(256) k_inverse(const float* __restrict__ h,
                                                  const float* __restrict__ ws,
                                                  const float* __restrict__ wconv,
                                                  const float* __restrict__ bconv,
                                                  float* __restrict__ hout, int layer,
                                                  int do_gelu) {
  constexpr int TN = 32;
  int b = blockIdx.y;
  int n0 = blockIdx.x * TN;
  int tid = threadIdx.x;
  int tg = tid & 7;   // c0 = tg*8
  int tn = tid >> 3;  // 0..31
  __shared__ __align__(16) float cs[cK * TN];  // [k][tn]
  __shared__ __align__(16) float sn[cK * TN];
  __shared__ __align__(16) float hT[cC * TN];  // [c][tn]
  __shared__ float ms[TN];
  const float* hb = h + (size_t)b * cC * cN;
  const float4* pk = (const float4*)(ws + OFF_PACK) + (size_t)b * cN;
  const float* FcB = ws + OFF_FCT + (size_t)b * cK * cC;
  const float* FsB = ws + OFF_FST + (size_t)b * cK * cC;
  const float* F0B = ws + OFF_F0 + (size_t)b * cC;
  int nn_l = tid & 31;
  int kc_l = tid >> 5;
  {
    float4 p = pk[n0 + nn_l];
    if (tid < TN) ms[tid] = p.w;
#pragma unroll
    for (int i = 0; i < 8; i++) {
      int c = kc_l + i * 8;
      hT[c * TN + nn_l] = hb[(size_t)c * cN + n0 + nn_l];
    }
#pragma unroll
    for (int i = 0; i < 16; i++) {
      int k = kc_l + i * 8;
      int kx = k >> 3, ky = k & 7;
      float ang = p.x * (kTwoPi * (float)kx) + p.y * (kTwoPi * (float)ky);
      float sv, cv;
      sincosf(ang, &sv, &cv);
      cs[k * TN + nn_l] = cv;
      sn[k * TN + nn_l] = sv;
    }
  }
  __syncthreads();
  int c0 = tg * 8;
  float acc[8] = {};
  for (int k = 0; k < cK; k++) {
    float cv = cs[k * TN + tn];
    float sv = sn[k * TN + tn];
    const float4* f4 = (const float4*)(FcB + (size_t)k * cC + c0);
    const float4* g4 = (const float4*)(FsB + (size_t)k * cC + c0);
    float4 fa = f4[0], fb = f4[1], ga = g4[0], gb = g4[1];
    acc[0] += cv * fa.x - sv * ga.x;
    acc[1] += cv * fa.y - sv * ga.y;
    acc[2] += cv * fa.z - sv * ga.z;
    acc[3] += cv * fa.w - sv * ga.w;
    acc[4] += cv * fb.x - sv * gb.x;
    acc[5] += cv * fb.y - sv * gb.y;
    acc[6] += cv * fb.z - sv * gb.z;
    acc[7] += cv * fb.w - sv * gb.w;
  }
  float mval = ms[tn];
  float cvv[8] = {};
  const float* wcl = wconv + (size_t)layer * cC * cC;
  for (int i = 0; i < cC; i++) {
    float hv = hT[i * TN + tn];
    const float4* w4 = (const float4*)(wcl + (size_t)i * cC + c0);
    float4 wa = w4[0], wb = w4[1];
    cvv[0] += hv * wa.x;
    cvv[1] += hv * wa.y;
    cvv[2] += hv * wa.z;
    cvv[3] += hv * wa.w;
    cvv[4] += hv * wb.x;
    cvv[5] += hv * wb.y;
    cvv[6] += hv * wb.z;
    cvv[7] += hv * wb.w;
  }
  float* ho = hout + (size_t)b * cC * cN + n0 + tn;
#pragma unroll
  for (int j = 0; j < 8; j++) {
    int c = c0 + j;
    float v = (F0B[c] + acc[j]) * mval + cvv[j] + bconv[layer * cC + c];
    if (do_gelu) v = gelu_f(v);
    ho[(size_t)c * cN] = v;
  }
}

// --- final MLP: gelu(h^T @ fc1 + b1) @ fc2 + b2
__global__ void __launch_bounds__(256) k_final(const float* __restrict__ h,
                                                const float* __restrict__ fc1_w,
                                                const float* __restrict__ fc1_b,
                                                const float* __restrict__ fc2_w,
                                                const float* __restrict__ fc2_b,
                                                float* __restrict__ out) {
  int b = blockIdx.y;
  int n0 = blockIdx.x * 64;
  int tid = threadIdx.x;
  int tn = tid & 63;
  int tg = tid >> 6;  // wave id: j0 = tg*32 (uniform per wave -> LDS broadcast)
  __shared__ __align__(16) float w1s[cC * 128];
  __shared__ __align__(16) float hT[cC * 64];
  __shared__ float red[4 * 64];
  const float* hb = h + (size_t)b * cC * cN;
#pragma unroll
  for (int i = 0; i < 16; i++) {
    int e = tid + i * 256;
    int c = e >> 6, nn = e & 63;
    hT[c * 64 + nn] = hb[(size_t)c * cN + n0 + nn];
  }
#pragma unroll
  for (int i = 0; i < 32; i++) {
    int e = tid + i * 256;
    w1s[e] = fc1_w[e];
  }
  __syncthreads();
  int j0 = tg * 32;
  float acc[32] = {};
  for (int c = 0; c < cC; c++) {
    float hv = hT[c * 64 + tn];
#pragma unroll
    for (int jj = 0; jj < 32; jj += 4) {
      float4 w4 = *(const float4*)&w1s[c * 128 + j0 + jj];
      acc[jj] += hv * w4.x;
      acc[jj + 1] += hv * w4.y;
      acc[jj + 2] += hv * w4.z;
      acc[jj + 3] += hv * w4.w;
    }
  }
  float s = 0.0f;
#pragma unroll
  for (int jj = 0; jj < 32; jj++) {
    int j = j0 + jj;
    float v = gelu_f(acc[jj] + fc1_b[j]);
    s += v * fc2_w[j];
  }
  red[tg * 64 + tn] = s;
  __syncthreads();
  if (tg == 0) {
    float r = red[tn] + red[64 + tn] + red[128 + tn] + red[192 + tn] + fc2_b[0];
    out[(size_t)b * cN + n0 + tn] = r;
  }
}

extern "C" void kernel_launch(void* const* d_in, const int* in_sizes, int n_in,
                              void* d_out, int out_size, void* d_ws, size_t ws_size,
                              hipStream_t stream) {
  const float* x = (const float*)d_in[0];
  const float* fc0_w = (const float*)d_in[1];
  const float* fc0_b = (const float*)d_in[2];
  const float* wc1 = (const float*)d_in[3];
  const float* wc2 = (const float*)d_in[4];
  const float* ws1 = (const float*)d_in[5];
  const float* ws2 = (const float*)d_in[6];
  const float* w01 = (const float*)d_in[7];
  const float* w02 = (const float*)d_in[8];
  const float* wconv = (const float*)d_in[9];
  const float* bconv = (const float*)d_in[10];
  const float* fc1_w = (const float*)d_in[11];
  const float* fc1_b = (const float*)d_in[12];
  const float* fc2_w = (const float*)d_in[13];
  const float* fc2_b = (const float*)d_in[14];
  float* ws = (float*)d_ws;
  float* out = (float*)d_out;
  float* hA = ws + OFF_HA;
  float* hB = ws + OFF_HB;

  hipLaunchKernelGGL(k_prep, dim3(cB * cN / 256), dim3(256), 0, stream, x, fc0_w, fc0_b, ws);
  float* hcur = hA;
  float* hnext = hB;
  for (int l = 0; l < cNL; l++) {
    hipLaunchKernelGGL(k_forward, dim3(16, cB), dim3(256), 0, stream, hcur, ws,
                       ws + OFF_XC, ws + OFF_XS, ws + OFF_X0);
    hipLaunchKernelGGL(k_lowrank, dim3(cB), dim3(cK), 0, stream, ws + OFF_XC,
                       ws + OFF_XS, ws + OFF_X0, wc1, wc2, ws1, ws2, w01, w02,
                       ws + OFF_FCT, ws + OFF_FST, ws + OFF_F0, l);
    hipLaunchKernelGGL(k_inverse, dim3(cN / 32, cB), dim3(256), 0, stream, hcur, ws,
                       wconv, bconv, hnext, l, (l != cNL - 1) ? 1 : 0);
    float* tswap = hcur;
    hcur = hnext;
    hnext = tswap;
  }
  hipLaunchKernelGGL(k_final, dim3(cN / 64, cB), dim3(256), 0, stream, hcur, fc1_w,
                     fc1_b, fc2_w, fc2_b, out);
}

// Round 2
// 2183.004 us; speedup vs baseline: 1.5839x; 1.5839x over previous
//
#include <hip/hip_runtime.h>
#include <math.h>

namespace {
constexpr int cB = 16, cN = 8192, cC = 64, cK = 128, cR = 4, cNL = 4;
constexpr float kTwoPi = 6.28318530717958647692f;

// workspace layout (float offsets)
constexpr size_t OFF_H     = 0;                                   // B*C*N
constexpr size_t OFF_PACKA = (size_t)cB * cC * cN;                // 8,388,608  (B*N float4)
constexpr size_t OFF_PACKB = OFF_PACKA + (size_t)cB * cN * 4;     // (B*N float4)
constexpr size_t OFF_PACKC = OFF_PACKB + (size_t)cB * cN * 4;     // (B*N float2)
constexpr size_t OFF_XC    = OFF_PACKC + (size_t)cB * cN * 2;
constexpr size_t OFF_XS    = OFF_XC + (size_t)cB * cC * cK;
constexpr size_t OFF_FCT   = OFF_XS + (size_t)cB * cC * cK;
constexpr size_t OFF_FST   = OFF_FCT + (size_t)cB * cK * cC;
constexpr size_t OFF_F0    = OFF_FST + (size_t)cB * cK * cC;
// end = 10,224,640 floats = 40.9 MB (round-1 used 71.3 MB OK)

__device__ __forceinline__ float gelu_f(float x) {
  return 0.5f * x * (1.0f + erff(x * 0.7071067811865475244f));
}

struct cpx { float x, y; };
__device__ __forceinline__ cpx cmul(cpx a, cpx b) {
  cpx r;
  r.x = fmaf(a.x, b.x, -(a.y * b.y));
  r.y = fmaf(a.x, b.y, a.y * b.x);
  return r;
}

// thread g (0..7) produces modes k = 8g+ky and 64+8g+ky (ky=0..7) for one point.
// pA = (cos ax, sin ax, cos ay, sin ay); pB = (cos 8ax, sin 8ax, cos 4ay, sin 4ay)
__device__ __forceinline__ void compute_modes(int g, float4 pA, float4 pB,
                                              float* cw_row, float* sw_row) {
  cpx ex{pA.x, pA.y}, ey{pA.z, pA.w}, ex8{pB.x, pB.y}, ey4{pB.z, pB.w};
  cpx eyp[8];
  eyp[0] = {1.0f, 0.0f};
  eyp[1] = ey;
  eyp[2] = cmul(ey, ey);
  eyp[3] = cmul(eyp[2], ey);
  eyp[4] = ey4;                 // exact from prep
  eyp[5] = cmul(ey4, ey);
  eyp[6] = cmul(ey4, eyp[2]);
  eyp[7] = cmul(ey4, eyp[3]);
  cpx r{1.0f, 0.0f};
  cpx t = ex;
  if (g & 1) r = t;
  t = cmul(t, t);               // ex^2
  if (g & 2) r = cmul(r, t);
  t = cmul(t, t);               // ex^4
  if (g & 4) r = cmul(r, t);    // r = ex^g
  cpx r8 = cmul(r, ex8);        // ex^(g+8), ex8 exact
  float mc[8], msn[8], mc2[8], msn2[8];
#pragma unroll
  for (int ky = 0; ky < 8; ky++) {
    cpx m1 = cmul(r, eyp[ky]);
    cpx m2 = cmul(r8, eyp[ky]);
    mc[ky] = m1.x; msn[ky] = m1.y;
    mc2[ky] = m2.x; msn2[ky] = m2.y;
  }
  *(float4*)&cw_row[8 * g]      = make_float4(mc[0], mc[1], mc[2], mc[3]);
  *(float4*)&cw_row[8 * g + 4]  = make_float4(mc[4], mc[5], mc[6], mc[7]);
  *(float4*)&cw_row[64 + 8 * g]     = make_float4(mc2[0], mc2[1], mc2[2], mc2[3]);
  *(float4*)&cw_row[64 + 8 * g + 4] = make_float4(mc2[4], mc2[5], mc2[6], mc2[7]);
  *(float4*)&sw_row[8 * g]      = make_float4(msn[0], msn[1], msn[2], msn[3]);
  *(float4*)&sw_row[8 * g + 4]  = make_float4(msn[4], msn[5], msn[6], msn[7]);
  *(float4*)&sw_row[64 + 8 * g]     = make_float4(msn2[0], msn2[1], msn2[2], msn2[3]);
  *(float4*)&sw_row[64 + 8 * g + 4] = make_float4(msn2[4], msn2[5], msn2[6], msn2[7]);
}
}  // namespace

// --- prep: fc0 into (B,C,N), per-point phase factors, zero Xc/Xs
__global__ void __launch_bounds__(256) k_prep(const float* __restrict__ x,
                                              const float* __restrict__ fc0_w,
                                              const float* __restrict__ fc0_b,
                                              float* __restrict__ ws) {
  int t = blockIdx.x * 256 + threadIdx.x;  // 0..B*N-1
  int b = t >> 13;
  int n = t & (cN - 1);
  const float* xp = x + (size_t)t * 7;
  float f0 = xp[0], f1 = xp[1], f2 = xp[2];
  float gx = xp[3], gy = xp[4], w = xp[5], m = xp[6];
  float ax = kTwoPi * gx, ay = kTwoPi * gy;
  float sx, cx, sy, cy, s8x, c8x, s4y, c4y;
  sincosf(ax, &sx, &cx);
  sincosf(ay, &sy, &cy);
  sincosf(8.0f * ax, &s8x, &c8x);
  sincosf(4.0f * ay, &s4y, &c4y);
  ((float4*)(ws + OFF_PACKA))[t] = make_float4(cx, sx, cy, sy);
  ((float4*)(ws + OFF_PACKB))[t] = make_float4(c8x, s8x, c4y, s4y);
  ((float2*)(ws + OFF_PACKC))[t] = make_float2(w * (float)cN * m, m);
  float* h = ws + OFF_H + (size_t)b * cC * cN + n;
#pragma unroll
  for (int c = 0; c < cC; c++) {
    float v = fc0_b[c] + f0 * fc0_w[c] + f1 * fc0_w[cC + c] + f2 * fc0_w[2 * cC + c];
    h[(size_t)c * cN] = v;
  }
  float* acc = ws + OFF_XC;
  for (int i = t; i < 2 * cB * cC * cK; i += cB * cN) acc[i] = 0.0f;
}

// --- forward transform: Xc[b,c,k] += sum_n h*a*cos, Xs += sum_n h*a*sin
__global__ void __launch_bounds__(256, 2) k_forward(const float* __restrict__ hg,
                                                    const float* __restrict__ ws,
                                                    float* Xc, float* Xs) {
  constexpr int TN = 32, S_CHUNK = 256;
  __shared__ __align__(16) float smem[2112 + 4224 + 4224];
  float* hs = smem;                // [c][33]
  float* cw = smem + 2112;         // [nn][132]
  float* sw = smem + 2112 + 4224;  // [nn][132]
  int b = blockIdx.y;
  int n_base = blockIdx.x * S_CHUNK;
  int tid = threadIdx.x;
  int half = tid >> 7;
  int tc = (tid >> 4) & 7;  // c0 = tc*8
  int tk = tid & 15;        // k = 4tk+q / 64+4tk+q
  int g = tid >> 5, nn = tid & 31;
  const float4* pA = (const float4*)(ws + OFF_PACKA) + (size_t)b * cN;
  const float4* pB = (const float4*)(ws + OFF_PACKB) + (size_t)b * cN;
  const float2* pC = (const float2*)(ws + OFF_PACKC) + (size_t)b * cN;
  const float* hb = hg + (size_t)b * cC * cN;
  float accC[8][8] = {}, accS[8][8] = {};
  for (int t0 = 0; t0 < S_CHUNK; t0 += TN) {
    int n0 = n_base + t0;
    float4 a4 = pA[n0 + nn];
    float4 b4 = pB[n0 + nn];
    float2 c2 = pC[n0 + nn];
    __syncthreads();  // previous tile fully consumed
#pragma unroll
    for (int i = 0; i < 8; i++) {
      int c = g + 8 * i;
      hs[c * 33 + nn] = hb[(size_t)c * cN + n0 + nn] * c2.x;
    }
    compute_modes(g, a4, b4, &cw[nn * 132], &sw[nn * 132]);
    __syncthreads();
    int sbase = half * 16;
#pragma unroll 2
    for (int u = 0; u < 16; u++) {
      int s = sbase + u;
      float hv[8];
#pragma unroll
      for (int j = 0; j < 8; j++) hv[j] = hs[(tc * 8 + j) * 33 + s];
      float4 cA = *(const float4*)&cw[s * 132 + 4 * tk];
      float4 cB2 = *(const float4*)&cw[s * 132 + 64 + 4 * tk];
      float4 sA = *(const float4*)&sw[s * 132 + 4 * tk];
      float4 sB2 = *(const float4*)&sw[s * 132 + 64 + 4 * tk];
      float cc[8] = {cA.x, cA.y, cA.z, cA.w, cB2.x, cB2.y, cB2.z, cB2.w};
      float ss[8] = {sA.x, sA.y, sA.z, sA.w, sB2.x, sB2.y, sB2.z, sB2.w};
#pragma unroll
      for (int j = 0; j < 8; j++)
#pragma unroll
        for (int q = 0; q < 8; q++) {
          accC[j][q] = fmaf(hv[j], cc[q], accC[j][q]);
          accS[j][q] = fmaf(hv[j], ss[q], accS[j][q]);
        }
    }
  }
  // merge halves through LDS (stride 66 -> 2-way banks, free), then atomics
  float* red = smem + 2112;  // 8448 floats available
  __syncthreads();
  if (half == 1) {
    float* dst = red + (tid - 128) * 66;
#pragma unroll
    for (int j = 0; j < 8; j++)
#pragma unroll
      for (int q = 0; q < 8; q++) dst[j * 8 + q] = accC[j][q];
  }
  __syncthreads();
  if (half == 0) {
    const float* src = red + tid * 66;
#pragma unroll
    for (int j = 0; j < 8; j++)
#pragma unroll
      for (int q = 0; q < 8; q++) accC[j][q] += src[j * 8 + q];
  }
  __syncthreads();
  if (half == 1) {
    float* dst = red + (tid - 128) * 66;
#pragma unroll
    for (int j = 0; j < 8; j++)
#pragma unroll
      for (int q = 0; q < 8; q++) dst[j * 8 + q] = accS[j][q];
  }
  __syncthreads();
  if (half == 0) {
    const float* src = red + tid * 66;
    float* xcb = Xc + (size_t)b * cC * cK;
    float* xsb = Xs + (size_t)b * cC * cK;
#pragma unroll
    for (int j = 0; j < 8; j++) {
      int c = tc * 8 + j;
#pragma unroll
      for (int q = 0; q < 8; q++) {
        int k = (q < 4) ? (4 * tk + q) : (64 + 4 * tk + (q - 4));
        atomicAdd(&xcb[c * cK + k], accC[j][q]);
        atomicAdd(&xsb[c * cK + k], accS[j][q] + src[j * 8 + q]);
      }
    }
  }
}

// --- low-rank mixing per (b,k); X0 = Xc[:, :, 0]; zeroes Xc/Xs for next layer
__global__ void k_lowrank(float* Xc, float* Xs, const float* __restrict__ wc1,
                          const float* __restrict__ wc2, const float* __restrict__ ws1,
                          const float* __restrict__ ws2, const float* __restrict__ w01,
                          const float* __restrict__ w02, float* __restrict__ FcT,
                          float* __restrict__ FsT, float* __restrict__ F0, int layer) {
  int b = blockIdx.x;
  int k = threadIdx.x;
  float* xcb = Xc + (size_t)b * cC * cK;
  float* xsb = Xs + (size_t)b * cC * cK;
  if (k == 0) {  // X0 path from column 0 (mode (0,0) == ones) BEFORE zeroing
    float t[cR] = {};
    for (int i = 0; i < cC; i++) {
      float xv = xcb[(size_t)i * cK];
#pragma unroll
      for (int r = 0; r < cR; r++) t[r] += xv * w01[((size_t)layer * cC + i) * cR + r];
    }
    for (int o = 0; o < cC; o++) {
      float f = 0.0f;
#pragma unroll
      for (int r = 0; r < cR; r++) f += t[r] * w02[((size_t)layer * cR + r) * cC + o];
      F0[b * cC + o] = f / (float)cN;
    }
  }
  const float* c1 = wc1 + (size_t)layer * cC * cR * cK;
  const float* s1 = ws1 + (size_t)layer * cC * cR * cK;
  const float* c2 = wc2 + (size_t)layer * cR * cC * cK;
  const float* s2 = ws2 + (size_t)layer * cR * cC * cK;
  float A1[cR] = {}, A2[cR] = {}, B1[cR] = {}, B2[cR] = {};
  for (int i = 0; i < cC; i++) {
    size_t idx = (size_t)i * cK + k;
    float xcv = xcb[idx]; xcb[idx] = 0.0f;
    float xsv = -xsb[idx]; xsb[idx] = 0.0f;  // x_s = -sum(h*a*sin)
#pragma unroll
    for (int r = 0; r < cR; r++) {
      float w1c = c1[((size_t)i * cR + r) * cK + k];
      float w1sv = s1[((size_t)i * cR + r) * cK + k];
      A1[r] += xcv * w1c;
      A2[r] += xcv * w1sv;
      B1[r] += xsv * w1c;
      B2[r] += xsv * w1sv;
    }
  }
  const float scale = 2.0f / (float)cN;  // inv_sqrt^2 * (2x from inverse transform)
  float* fct = FcT + ((size_t)b * cK + k) * cC;
  float* fst = FsT + ((size_t)b * cK + k) * cC;
  for (int o = 0; o < cC; o++) {
    float fc = 0.0f, fs = 0.0f;
#pragma unroll
    for (int r = 0; r < cR; r++) {
      float w2c = c2[((size_t)r * cC + o) * cK + k];
      float w2s = s2[((size_t)r * cC + o) * cK + k];
      fc += A1[r] * w2c - B2[r] * w2s;
      fs += B1[r] * w2c + A2[r] * w2s;
    }
    fct[o] = scale * fc;
    fst[o] = scale * fs;
  }
}

// --- inverse transform + conv + bias + gelu, in-place on h
__global__ void __launch_bounds__(256) k_inverse(float* h, const float* __restrict__ ws,
                                                 const float* __restrict__ wconv,
                                                 const float* __restrict__ bconv,
                                                 int layer, int do_gelu) {
  constexpr int TN = 32;
  __shared__ __align__(16) float smem[4224 + 4224 + 2112 + 32];
  float* cs = smem;
  float* sn = smem + 4224;
  float* hT = smem + 8448;   // [c][33]
  float* msk = smem + 10560;
  int b = blockIdx.y;
  int n0 = blockIdx.x * TN;
  int tid = threadIdx.x;
  int tg = tid & 7;   // c0 = tg*8
  int tn = tid >> 3;  // 0..31
  int g = tid >> 5, nn = tid & 31;
  const float4* pA = (const float4*)(ws + OFF_PACKA) + (size_t)b * cN;
  const float4* pB = (const float4*)(ws + OFF_PACKB) + (size_t)b * cN;
  const float2* pC = (const float2*)(ws + OFF_PACKC) + (size_t)b * cN;
  float* hb = h + (size_t)b * cC * cN;
  float4 a4 = pA[n0 + nn];
  float4 b4 = pB[n0 + nn];
  float2 c2 = pC[n0 + nn];
  if (g == 0) msk[nn] = c2.y;
#pragma unroll
  for (int i = 0; i < 8; i++) {
    int c = g + 8 * i;
    hT[c * 33 + nn] = hb[(size_t)c * cN + n0 + nn];
  }
  compute_modes(g, a4, b4, &cs[nn * 132], &sn[nn * 132]);
  __syncthreads();
  int c0 = tg * 8;
  float acc[8] = {};
  const float* FcB = ws + OFF_FCT + (size_t)b * cK * cC;
  const float* FsB = ws + OFF_FST + (size_t)b * cK * cC;
  for (int k = 0; k < cK; k++) {
    float cv = cs[tn * 132 + k];
    float sv = sn[tn * 132 + k];
    float4 fa = *(const float4*)&FcB[(size_t)k * cC + c0];
    float4 fb = *(const float4*)&FcB[(size_t)k * cC + c0 + 4];
    float4 ga = *(const float4*)&FsB[(size_t)k * cC + c0];
    float4 gb = *(const float4*)&FsB[(size_t)k * cC + c0 + 4];
    acc[0] = fmaf(cv, fa.x, fmaf(-sv, ga.x, acc[0]));
    acc[1] = fmaf(cv, fa.y, fmaf(-sv, ga.y, acc[1]));
    acc[2] = fmaf(cv, fa.z, fmaf(-sv, ga.z, acc[2]));
    acc[3] = fmaf(cv, fa.w, fmaf(-sv, ga.w, acc[3]));
    acc[4] = fmaf(cv, fb.x, fmaf(-sv, gb.x, acc[4]));
    acc[5] = fmaf(cv, fb.y, fmaf(-sv, gb.y, acc[5]));
    acc[6] = fmaf(cv, fb.z, fmaf(-sv, gb.z, acc[6]));
    acc[7] = fmaf(cv, fb.w, fmaf(-sv, gb.w, acc[7]));
  }
  float cvv[8] = {};
  const float* wcl = wconv + (size_t)layer * cC * cC;
  for (int i = 0; i < cC; i++) {
    float hvv = hT[i * 33 + tn];
    float4 wa = *(const float4*)&wcl[(size_t)i * cC + c0];
    float4 wb = *(const float4*)&wcl[(size_t)i * cC + c0 + 4];
    cvv[0] = fmaf(hvv, wa.x, cvv[0]);
    cvv[1] = fmaf(hvv, wa.y, cvv[1]);
    cvv[2] = fmaf(hvv, wa.z, cvv[2]);
    cvv[3] = fmaf(hvv, wa.w, cvv[3]);
    cvv[4] = fmaf(hvv, wb.x, cvv[4]);
    cvv[5] = fmaf(hvv, wb.y, cvv[5]);
    cvv[6] = fmaf(hvv, wb.z, cvv[6]);
    cvv[7] = fmaf(hvv, wb.w, cvv[7]);
  }
  const float* F0B = ws + OFF_F0 + (size_t)b * cC;
  float mval = msk[tn];
  float* ho = hb + n0 + tn;
#pragma unroll
  for (int j = 0; j < 8; j++) {
    int c = c0 + j;
    float v = fmaf(F0B[c] + acc[j], mval, cvv[j] + bconv[layer * cC + c]);
    if (do_gelu) v = gelu_f(v);
    ho[(size_t)c * cN] = v;
  }
}

// --- final MLP: gelu(h^T @ fc1 + b1) @ fc2 + b2
__global__ void __launch_bounds__(256) k_final(const float* __restrict__ h,
                                               const float* __restrict__ fc1_w,
                                               const float* __restrict__ fc1_b,
                                               const float* __restrict__ fc2_w,
                                               const float* __restrict__ fc2_b,
                                               float* __restrict__ out) {
  int b = blockIdx.y;
  int n0 = blockIdx.x * 64;
  int tid = threadIdx.x;
  int tn = tid & 63;
  int tg = tid >> 6;
  __shared__ __align__(16) float w1s[cC * 128];
  __shared__ __align__(16) float hT[cC * 64];
  __shared__ float red[4 * 64];
  const float* hb = h + (size_t)b * cC * cN;
#pragma unroll
  for (int i = 0; i < 16; i++) {
    int e = tid + i * 256;
    int c = e >> 6, nnx = e & 63;
    hT[c * 64 + nnx] = hb[(size_t)c * cN + n0 + nnx];
  }
#pragma unroll
  for (int i = 0; i < 32; i++) {
    int e = tid + i * 256;
    w1s[e] = fc1_w[e];
  }
  __syncthreads();
  int j0 = tg * 32;
  float acc[32] = {};
  for (int c = 0; c < cC; c++) {
    float hv = hT[c * 64 + tn];
#pragma unroll
    for (int jj = 0; jj < 32; jj += 4) {
      float4 w4 = *(const float4*)&w1s[c * 128 + j0 + jj];
      acc[jj] += hv * w4.x;
      acc[jj + 1] += hv * w4.y;
      acc[jj + 2] += hv * w4.z;
      acc[jj + 3] += hv * w4.w;
    }
  }
  float s = 0.0f;
#pragma unroll
  for (int jj = 0; jj < 32; jj++) {
    int j = j0 + jj;
    float v = gelu_f(acc[jj] + fc1_b[j]);
    s += v * fc2_w[j];
  }
  red[tg * 64 + tn] = s;
  __syncthreads();
  if (tg == 0) {
    float r = red[tn] + red[64 + tn] + red[128 + tn] + red[192 + tn] + fc2_b[0];
    out[(size_t)b * cN + n0 + tn] = r;
  }
}

extern "C" void kernel_launch(void* const* d_in, const int* in_sizes, int n_in,
                              void* d_out, int out_size, void* d_ws, size_t ws_size,
                              hipStream_t stream) {
  const float* x = (const float*)d_in[0];
  const float* fc0_w = (const float*)d_in[1];
  const float* fc0_b = (const float*)d_in[2];
  const float* wc1 = (const float*)d_in[3];
  const float* wc2 = (const float*)d_in[4];
  const float* ws1 = (const float*)d_in[5];
  const float* ws2 = (const float*)d_in[6];
  const float* w01 = (const float*)d_in[7];
  const float* w02 = (const float*)d_in[8];
  const float* wconv = (const float*)d_in[9];
  const float* bconv = (const float*)d_in[10];
  const float* fc1_w = (const float*)d_in[11];
  const float* fc1_b = (const float*)d_in[12];
  const float* fc2_w = (const float*)d_in[13];
  const float* fc2_b = (const float*)d_in[14];
  float* ws = (float*)d_ws;
  float* out = (float*)d_out;
  float* h = ws + OFF_H;

  hipLaunchKernelGGL(k_prep, dim3(cB * cN / 256), dim3(256), 0, stream, x, fc0_w, fc0_b, ws);
  for (int l = 0; l < cNL; l++) {
    hipLaunchKernelGGL(k_forward, dim3(32, cB), dim3(256), 0, stream, h, ws,
                       ws + OFF_XC, ws + OFF_XS);
    hipLaunchKernelGGL(k_lowrank, dim3(cB), dim3(cK), 0, stream, ws + OFF_XC,
                       ws + OFF_XS, wc1, wc2, ws1, ws2, w01, w02,
                       ws + OFF_FCT, ws + OFF_FST, ws + OFF_F0, l);
    hipLaunchKernelGGL(k_inverse, dim3(cN / 32, cB), dim3(256), 0, stream, h, ws,
                       wconv, bconv, l, (l != cNL - 1) ? 1 : 0);
  }
  hipLaunchKernelGGL(k_final, dim3(cN / 64, cB), dim3(256), 0, stream, h, fc1_w,
                     fc1_b, fc2_w, fc2_b, out);
}

// Round 3
// 871.667 us; speedup vs baseline: 3.9666x; 2.5044x over previous
//
#include <hip/hip_runtime.h>
#include <math.h>

namespace {
constexpr int cB = 16, cN = 8192, cC = 64, cK = 128, cR = 4, cNL = 4;
constexpr float kTwoPi = 6.28318530717958647692f;

// workspace layout (float offsets)
constexpr size_t OFF_H     = 0;                                // 8,388,608
constexpr size_t OFF_PACKA = (size_t)cB * cC * cN;             // +524,288
constexpr size_t OFF_PACKB = OFF_PACKA + (size_t)cB * cN * 4;  // +524,288
constexpr size_t OFF_PACKC = OFF_PACKB + (size_t)cB * cN * 4;  // +262,144
constexpr size_t OFF_PC    = OFF_PACKC + (size_t)cB * cN * 2;  // 256 blocks * 8192
constexpr size_t OFF_PS    = OFF_PC + (size_t)256 * 8192;
constexpr size_t OFF_XC    = OFF_PS + (size_t)256 * 8192;
constexpr size_t OFF_XS    = OFF_XC + (size_t)cB * cC * cK;
constexpr size_t OFF_FCT   = OFF_XS + (size_t)cB * cC * cK;
constexpr size_t OFF_FST   = OFF_FCT + (size_t)cB * cK * cC;
constexpr size_t OFF_F0    = OFF_FST + (size_t)cB * cK * cC;
// end = 14,418,944 floats = 57.7 MB

__device__ __forceinline__ float gelu_f(float x) {
  return 0.5f * x * (1.0f + erff(x * 0.7071067811865475244f));
}

struct cpx { float x, y; };
__device__ __forceinline__ cpx cmul(cpx a, cpx b) {
  cpx r;
  r.x = fmaf(a.x, b.x, -(a.y * b.y));
  r.y = fmaf(a.x, b.y, a.y * b.x);
  return r;
}

// thread g (0..7) produces modes k = 8g+ky and 64+8g+ky (ky=0..7) for one point.
__device__ __forceinline__ void compute_modes(int g, float4 pA, float4 pB,
                                              float* cw_row, float* sw_row) {
  cpx ex{pA.x, pA.y}, ey{pA.z, pA.w}, ex8{pB.x, pB.y}, ey4{pB.z, pB.w};
  cpx eyp[8];
  eyp[0] = {1.0f, 0.0f};
  eyp[1] = ey;
  eyp[2] = cmul(ey, ey);
  eyp[3] = cmul(eyp[2], ey);
  eyp[4] = ey4;
  eyp[5] = cmul(ey4, ey);
  eyp[6] = cmul(ey4, eyp[2]);
  eyp[7] = cmul(ey4, eyp[3]);
  cpx r{1.0f, 0.0f};
  cpx t = ex;
  if (g & 1) r = t;
  t = cmul(t, t);
  if (g & 2) r = cmul(r, t);
  t = cmul(t, t);
  if (g & 4) r = cmul(r, t);
  cpx r8 = cmul(r, ex8);
  float mc[8], msn[8], mc2[8], msn2[8];
#pragma unroll
  for (int ky = 0; ky < 8; ky++) {
    cpx m1 = cmul(r, eyp[ky]);
    cpx m2 = cmul(r8, eyp[ky]);
    mc[ky] = m1.x; msn[ky] = m1.y;
    mc2[ky] = m2.x; msn2[ky] = m2.y;
  }
  *(float4*)&cw_row[8 * g]          = make_float4(mc[0], mc[1], mc[2], mc[3]);
  *(float4*)&cw_row[8 * g + 4]      = make_float4(mc[4], mc[5], mc[6], mc[7]);
  *(float4*)&cw_row[64 + 8 * g]     = make_float4(mc2[0], mc2[1], mc2[2], mc2[3]);
  *(float4*)&cw_row[64 + 8 * g + 4] = make_float4(mc2[4], mc2[5], mc2[6], mc2[7]);
  *(float4*)&sw_row[8 * g]          = make_float4(msn[0], msn[1], msn[2], msn[3]);
  *(float4*)&sw_row[8 * g + 4]      = make_float4(msn[4], msn[5], msn[6], msn[7]);
  *(float4*)&sw_row[64 + 8 * g]     = make_float4(msn2[0], msn2[1], msn2[2], msn2[3]);
  *(float4*)&sw_row[64 + 8 * g + 4] = make_float4(msn2[4], msn2[5], msn2[6], msn2[7]);
}
}  // namespace

// --- prep: fc0 into (B,C,N), per-point phase factors
__global__ void __launch_bounds__(256) k_prep(const float* __restrict__ x,
                                              const float* __restrict__ fc0_w,
                                              const float* __restrict__ fc0_b,
                                              float* __restrict__ ws) {
  int t = blockIdx.x * 256 + threadIdx.x;
  int b = t >> 13;
  int n = t & (cN - 1);
  const float* xp = x + (size_t)t * 7;
  float f0 = xp[0], f1 = xp[1], f2 = xp[2];
  float gx = xp[3], gy = xp[4], w = xp[5], m = xp[6];
  float ax = kTwoPi * gx, ay = kTwoPi * gy;
  float sx, cx, sy, cy, s8x, c8x, s4y, c4y;
  sincosf(ax, &sx, &cx);
  sincosf(ay, &sy, &cy);
  sincosf(8.0f * ax, &s8x, &c8x);
  sincosf(4.0f * ay, &s4y, &c4y);
  ((float4*)(ws + OFF_PACKA))[t] = make_float4(cx, sx, cy, sy);
  ((float4*)(ws + OFF_PACKB))[t] = make_float4(c8x, s8x, c4y, s4y);
  ((float2*)(ws + OFF_PACKC))[t] = make_float2(w * (float)cN * m, m);
  float* h = ws + OFF_H + (size_t)b * cC * cN + n;
#pragma unroll
  for (int c = 0; c < cC; c++) {
    float v = fc0_b[c] + f0 * fc0_w[c] + f1 * fc0_w[cC + c] + f2 * fc0_w[2 * cC + c];
    h[(size_t)c * cN] = v;
  }
}

// --- forward: per-block partial Xc/Xs (64c x 128k), no atomics
__global__ void __launch_bounds__(256) k_forward(const float* __restrict__ hg,
                                                 const float* __restrict__ ws,
                                                 float* __restrict__ Pc,
                                                 float* __restrict__ Ps) {
  __shared__ __align__(16) float hs[64 * 33];
  __shared__ __align__(16) float cw[32 * 132];
  __shared__ __align__(16) float sw[32 * 132];
  int b = blockIdx.y, nb = blockIdx.x;
  int n_base = nb * 512;
  int tid = threadIdx.x;
  int g = tid >> 5, nn = tid & 31;   // basis/staging mapping
  int tc = tid >> 5, tkq = tid & 31; // compute mapping: c0=tc*8, k=tkq*4+q
  const float4* pA = (const float4*)(ws + OFF_PACKA) + (size_t)b * cN;
  const float4* pB = (const float4*)(ws + OFF_PACKB) + (size_t)b * cN;
  const float2* pC = (const float2*)(ws + OFF_PACKC) + (size_t)b * cN;
  const float* hb = hg + (size_t)b * cC * cN;
  float accC[8][4] = {}, accS[8][4] = {};
  // prefetch tile 0
  float4 a4 = pA[n_base + nn];
  float4 b4 = pB[n_base + nn];
  float2 c2 = pC[n_base + nn];
  float hv8[8];
#pragma unroll
  for (int i = 0; i < 8; i++) hv8[i] = hb[(size_t)(g + 8 * i) * cN + n_base + nn];
  for (int tile = 0; tile < 16; tile++) {
    __syncthreads();
#pragma unroll
    for (int i = 0; i < 8; i++) hs[(g + 8 * i) * 33 + nn] = hv8[i] * c2.x;
    compute_modes(g, a4, b4, &cw[nn * 132], &sw[nn * 132]);
    if (tile < 15) {  // software-pipelined prefetch of next tile
      int n0 = n_base + (tile + 1) * 32;
      a4 = pA[n0 + nn];
      b4 = pB[n0 + nn];
      c2 = pC[n0 + nn];
#pragma unroll
      for (int i = 0; i < 8; i++) hv8[i] = hb[(size_t)(g + 8 * i) * cN + n0 + nn];
    }
    __syncthreads();
#pragma unroll 2
    for (int s = 0; s < 32; s++) {
      float4 c4v = *(const float4*)&cw[s * 132 + tkq * 4];
      float4 s4v = *(const float4*)&sw[s * 132 + tkq * 4];
      float cc[4] = {c4v.x, c4v.y, c4v.z, c4v.w};
      float ss[4] = {s4v.x, s4v.y, s4v.z, s4v.w};
      float hvj[8];
#pragma unroll
      for (int j = 0; j < 8; j++) hvj[j] = hs[(tc * 8 + j) * 33 + s];
#pragma unroll
      for (int j = 0; j < 8; j++)
#pragma unroll
        for (int q = 0; q < 4; q++) {
          accC[j][q] = fmaf(hvj[j], cc[q], accC[j][q]);
          accS[j][q] = fmaf(hvj[j], ss[q], accS[j][q]);
        }
    }
  }
  float* pcb = Pc + (size_t)(b * 16 + nb) * 8192;
  float* psb = Ps + (size_t)(b * 16 + nb) * 8192;
#pragma unroll
  for (int j = 0; j < 8; j++) {
    int off = (tc * 8 + j) * 128 + tkq * 4;
    *(float4*)&pcb[off] = make_float4(accC[j][0], accC[j][1], accC[j][2], accC[j][3]);
    *(float4*)&psb[off] = make_float4(accS[j][0], accS[j][1], accS[j][2], accS[j][3]);
  }
}

// --- reduce 16 partials -> Xc/Xs
__global__ void __launch_bounds__(256) k_reduce(const float* __restrict__ Pc,
                                                const float* __restrict__ Ps,
                                                float* __restrict__ Xc,
                                                float* __restrict__ Xs) {
  int idx = blockIdx.x * 256 + threadIdx.x;  // 0..131071
  int b = idx >> 13;
  int rest = idx & 8191;
  float sc = 0.0f, ss = 0.0f;
#pragma unroll
  for (int nb = 0; nb < 16; nb++) {
    sc += Pc[(size_t)(b * 16 + nb) * 8192 + rest];
    ss += Ps[(size_t)(b * 16 + nb) * 8192 + rest];
  }
  Xc[idx] = sc;
  Xs[idx] = ss;
}

// --- low-rank mixing per (b,k); X0 = Xc[:, :, 0]
__global__ void k_lowrank(const float* __restrict__ Xc, const float* __restrict__ Xs,
                          const float* __restrict__ wc1, const float* __restrict__ wc2,
                          const float* __restrict__ ws1, const float* __restrict__ ws2,
                          const float* __restrict__ w01, const float* __restrict__ w02,
                          float* __restrict__ FcT, float* __restrict__ FsT,
                          float* __restrict__ F0, int layer) {
  int b = blockIdx.x;
  int k = threadIdx.x;
  const float* xcb = Xc + (size_t)b * cC * cK;
  const float* xsb = Xs + (size_t)b * cC * cK;
  if (k == 0) {
    float t[cR] = {};
    for (int i = 0; i < cC; i++) {
      float xv = xcb[(size_t)i * cK];
#pragma unroll
      for (int r = 0; r < cR; r++) t[r] += xv * w01[((size_t)layer * cC + i) * cR + r];
    }
    for (int o = 0; o < cC; o++) {
      float f = 0.0f;
#pragma unroll
      for (int r = 0; r < cR; r++) f += t[r] * w02[((size_t)layer * cR + r) * cC + o];
      F0[b * cC + o] = f / (float)cN;
    }
  }
  const float* c1 = wc1 + (size_t)layer * cC * cR * cK;
  const float* s1 = ws1 + (size_t)layer * cC * cR * cK;
  const float* c2 = wc2 + (size_t)layer * cR * cC * cK;
  const float* s2 = ws2 + (size_t)layer * cR * cC * cK;
  float A1[cR] = {}, A2[cR] = {}, B1[cR] = {}, B2[cR] = {};
  for (int i = 0; i < cC; i++) {
    size_t idx = (size_t)i * cK + k;
    float xcv = xcb[idx];
    float xsv = -xsb[idx];  // x_s = -sum(h*a*sin)
#pragma unroll
    for (int r = 0; r < cR; r++) {
      float w1c = c1[((size_t)i * cR + r) * cK + k];
      float w1sv = s1[((size_t)i * cR + r) * cK + k];
      A1[r] += xcv * w1c;
      A2[r] += xcv * w1sv;
      B1[r] += xsv * w1c;
      B2[r] += xsv * w1sv;
    }
  }
  const float scale = 2.0f / (float)cN;
  float* fct = FcT + ((size_t)b * cK + k) * cC;
  float* fst = FsT + ((size_t)b * cK + k) * cC;
  for (int o = 0; o < cC; o++) {
    float fc = 0.0f, fs = 0.0f;
#pragma unroll
    for (int r = 0; r < cR; r++) {
      float w2c = c2[((size_t)r * cC + o) * cK + k];
      float w2s = s2[((size_t)r * cC + o) * cK + k];
      fc += A1[r] * w2c - B2[r] * w2s;
      fs += B1[r] * w2c + A2[r] * w2s;
    }
    fct[o] = scale * fc;
    fst[o] = scale * fs;
  }
}

// --- inverse transform + conv + bias + gelu, LDS-staged F, in-place on h
__global__ void __launch_bounds__(256) k_inverse(float* __restrict__ h,
                                                 const float* __restrict__ ws,
                                                 const float* __restrict__ wconv,
                                                 const float* __restrict__ bconv,
                                                 int layer, int do_gelu) {
  __shared__ __align__(16) float bc[32 * 128];
  __shared__ __align__(16) float bs[32 * 128];
  __shared__ __align__(16) float fcs[32 * 64];
  __shared__ __align__(16) float fss[32 * 64];
  __shared__ __align__(16) float wcv[64 * 64];
  __shared__ float msk[128];
  int b = blockIdx.y;
  int n_blk = blockIdx.x * 128;
  int tid = threadIdx.x;
  // basis-gen mapping: 2 threads per point
  int p = tid >> 1, t = tid & 1;
  const float4* pA = (const float4*)(ws + OFF_PACKA) + (size_t)b * cN;
  const float4* pB = (const float4*)(ws + OFF_PACKB) + (size_t)b * cN;
  const float2* pC = (const float2*)(ws + OFF_PACKC) + (size_t)b * cN;
  float4 a4 = pA[n_blk + p];
  float4 b4 = pB[n_blk + p];
  if (t == 0) msk[p] = pC[n_blk + p].y;
  cpx ex{a4.x, a4.y}, ey{a4.z, a4.w}, ex8{b4.x, b4.y}, ey4{b4.z, b4.w};
  cpx ex2 = cmul(ex, ex);
  cpx ex4 = cmul(ex2, ex2);
  cpx ex12 = cmul(ex8, ex4);
  cpx eyp[8];
  eyp[0] = {1.0f, 0.0f};
  eyp[1] = ey;
  eyp[2] = cmul(ey, ey);
  eyp[3] = cmul(eyp[2], ey);
  eyp[4] = ey4;
  eyp[5] = cmul(ey4, ey);
  eyp[6] = cmul(ey4, eyp[2]);
  eyp[7] = cmul(ey4, eyp[3]);
  cpx e_t = (t == 0) ? cpx{1.0f, 0.0f} : ex;
  // stage wconv once
  const float* wcl = wconv + (size_t)layer * 4096;
#pragma unroll
  for (int i = 0; i < 4; i++) {
    int e = i * 1024 + tid * 4;
    *(float4*)&wcv[e] = *(const float4*)&wcl[e];
  }
  // F chunk 0 prefetch
  const float* FcB = ws + OFF_FCT + (size_t)b * cK * cC;
  const float* FsB = ws + OFF_FST + (size_t)b * cK * cC;
  float4 pf0 = *(const float4*)&FcB[tid * 4];
  float4 pf1 = *(const float4*)&FcB[1024 + tid * 4];
  float4 pf2 = *(const float4*)&FsB[tid * 4];
  float4 pf3 = *(const float4*)&FsB[1024 + tid * 4];
  // compute mapping
  int tn2 = tid & 31, tc = tid >> 5;
  int n0l = tn2 * 4, c0 = tc * 8;
  float acc[4][8] = {};
  for (int cc = 0; cc < 4; cc++) {
    __syncthreads();
    // write F chunk to LDS
    *(float4*)&fcs[tid * 4] = pf0;
    *(float4*)&fcs[1024 + tid * 4] = pf1;
    *(float4*)&fss[tid * 4] = pf2;
    *(float4*)&fss[1024 + tid * 4] = pf3;
    // basis gen for kx in {4cc+t, 4cc+t+2}
    cpx ra;
    if (cc == 0) ra = e_t;
    else if (cc == 1) ra = cmul(ex4, e_t);
    else if (cc == 2) ra = cmul(ex8, e_t);
    else ra = cmul(ex12, e_t);
    cpx rb = cmul(ra, ex2);
#pragma unroll
    for (int ky = 0; ky < 8; ky++) {
      cpx ma = cmul(ra, eyp[ky]);
      cpx mb = cmul(rb, eyp[ky]);
      int ka = (t * 8 + ky) * 128 + p;
      int kb = ((t + 2) * 8 + ky) * 128 + p;
      bc[ka] = ma.x; bs[ka] = ma.y;
      bc[kb] = mb.x; bs[kb] = mb.y;
    }
    // prefetch next F chunk
    if (cc < 3) {
      int off = (cc + 1) * 2048;
      pf0 = *(const float4*)&FcB[off + tid * 4];
      pf1 = *(const float4*)&FcB[off + 1024 + tid * 4];
      pf2 = *(const float4*)&FsB[off + tid * 4];
      pf3 = *(const float4*)&FsB[off + 1024 + tid * 4];
    }
    __syncthreads();
#pragma unroll 2
    for (int kk = 0; kk < 32; kk++) {
      float4 bcv = *(const float4*)&bc[kk * 128 + n0l];
      float4 bsv = *(const float4*)&bs[kk * 128 + n0l];
      float4 f0 = *(const float4*)&fcs[kk * 64 + c0];
      float4 f1 = *(const float4*)&fcs[kk * 64 + c0 + 4];
      float4 g0 = *(const float4*)&fss[kk * 64 + c0];
      float4 g1 = *(const float4*)&fss[kk * 64 + c0 + 4];
      float bn[4] = {bcv.x, bcv.y, bcv.z, bcv.w};
      float sn[4] = {bsv.x, bsv.y, bsv.z, bsv.w};
      float fcv[8] = {f0.x, f0.y, f0.z, f0.w, f1.x, f1.y, f1.z, f1.w};
      float fsv[8] = {g0.x, g0.y, g0.z, g0.w, g1.x, g1.y, g1.z, g1.w};
#pragma unroll
      for (int nq = 0; nq < 4; nq++)
#pragma unroll
        for (int j = 0; j < 8; j++)
          acc[nq][j] = fmaf(bn[nq], fcv[j], fmaf(-sn[nq], fsv[j], acc[nq][j]));
    }
  }
  // epilogue: (F0 + acc)*mask + conv + bias, gelu, store in place
  const float* F0B = ws + OFF_F0 + (size_t)b * cC;
  float4 fz0 = *(const float4*)&F0B[c0];
  float4 fz1 = *(const float4*)&F0B[c0 + 4];
  float f0v[8] = {fz0.x, fz0.y, fz0.z, fz0.w, fz1.x, fz1.y, fz1.z, fz1.w};
  float mv[4];
#pragma unroll
  for (int nq = 0; nq < 4; nq++) mv[nq] = msk[n0l + nq];
#pragma unroll
  for (int nq = 0; nq < 4; nq++)
#pragma unroll
    for (int j = 0; j < 8; j++) acc[nq][j] = (f0v[j] + acc[nq][j]) * mv[nq];
  float* hb = h + (size_t)b * cC * cN + n_blk;
  for (int i = 0; i < cC; i++) {
    float4 hv = *(const float4*)&hb[(size_t)i * cN + n0l];
    float4 w0 = *(const float4*)&wcv[i * 64 + c0];
    float4 w1 = *(const float4*)&wcv[i * 64 + c0 + 4];
    float hn[4] = {hv.x, hv.y, hv.z, hv.w};
    float wv[8] = {w0.x, w0.y, w0.z, w0.w, w1.x, w1.y, w1.z, w1.w};
#pragma unroll
    for (int nq = 0; nq < 4; nq++)
#pragma unroll
      for (int j = 0; j < 8; j++) acc[nq][j] = fmaf(hn[nq], wv[j], acc[nq][j]);
  }
  __syncthreads();  // all conv reads of h complete before in-place stores
#pragma unroll
  for (int j = 0; j < 8; j++) {
    int c = c0 + j;
    float bv = bconv[layer * cC + c];
    float4 outv;
    float v0 = acc[0][j] + bv, v1 = acc[1][j] + bv, v2 = acc[2][j] + bv, v3 = acc[3][j] + bv;
    if (do_gelu) { v0 = gelu_f(v0); v1 = gelu_f(v1); v2 = gelu_f(v2); v3 = gelu_f(v3); }
    outv = make_float4(v0, v1, v2, v3);
    *(float4*)&hb[(size_t)c * cN + n0l] = outv;
  }
}

// --- final MLP: gelu(h^T @ fc1 + b1) @ fc2 + b2
__global__ void __launch_bounds__(256) k_final(const float* __restrict__ h,
                                               const float* __restrict__ fc1_w,
                                               const float* __restrict__ fc1_b,
                                               const float* __restrict__ fc2_w,
                                               const float* __restrict__ fc2_b,
                                               float* __restrict__ out) {
  int b = blockIdx.y;
  int n0 = blockIdx.x * 64;
  int tid = threadIdx.x;
  int tn = tid & 63;
  int tg = tid >> 6;
  __shared__ __align__(16) float w1s[cC * 128];
  __shared__ __align__(16) float hT[cC * 64];
  __shared__ float red[4 * 64];
  const float* hb = h + (size_t)b * cC * cN;
#pragma unroll
  for (int i = 0; i < 16; i++) {
    int e = tid + i * 256;
    int c = e >> 6, nnx = e & 63;
    hT[c * 64 + nnx] = hb[(size_t)c * cN + n0 + nnx];
  }
#pragma unroll
  for (int i = 0; i < 32; i++) {
    int e = tid + i * 256;
    w1s[e] = fc1_w[e];
  }
  __syncthreads();
  int j0 = tg * 32;
  float acc[32] = {};
  for (int c = 0; c < cC; c++) {
    float hv = hT[c * 64 + tn];
#pragma unroll
    for (int jj = 0; jj < 32; jj += 4) {
      float4 w4 = *(const float4*)&w1s[c * 128 + j0 + jj];
      acc[jj] += hv * w4.x;
      acc[jj + 1] += hv * w4.y;
      acc[jj + 2] += hv * w4.z;
      acc[jj + 3] += hv * w4.w;
    }
  }
  float s = 0.0f;
#pragma unroll
  for (int jj = 0; jj < 32; jj++) {
    int j = j0 + jj;
    float v = gelu_f(acc[jj] + fc1_b[j]);
    s += v * fc2_w[j];
  }
  red[tg * 64 + tn] = s;
  __syncthreads();
  if (tg == 0) {
    float r = red[tn] + red[64 + tn] + red[128 + tn] + red[192 + tn] + fc2_b[0];
    out[(size_t)b * cN + n0 + tn] = r;
  }
}

extern "C" void kernel_launch(void* const* d_in, const int* in_sizes, int n_in,
                              void* d_out, int out_size, void* d_ws, size_t ws_size,
                              hipStream_t stream) {
  const float* x = (const float*)d_in[0];
  const float* fc0_w = (const float*)d_in[1];
  const float* fc0_b = (const float*)d_in[2];
  const float* wc1 = (const float*)d_in[3];
  const float* wc2 = (const float*)d_in[4];
  const float* ws1 = (const float*)d_in[5];
  const float* ws2 = (const float*)d_in[6];
  const float* w01 = (const float*)d_in[7];
  const float* w02 = (const float*)d_in[8];
  const float* wconv = (const float*)d_in[9];
  const float* bconv = (const float*)d_in[10];
  const float* fc1_w = (const float*)d_in[11];
  const float* fc1_b = (const float*)d_in[12];
  const float* fc2_w = (const float*)d_in[13];
  const float* fc2_b = (const float*)d_in[14];
  float* ws = (float*)d_ws;
  float* out = (float*)d_out;
  float* h = ws + OFF_H;

  hipLaunchKernelGGL(k_prep, dim3(cB * cN / 256), dim3(256), 0, stream, x, fc0_w, fc0_b, ws);
  for (int l = 0; l < cNL; l++) {
    hipLaunchKernelGGL(k_forward, dim3(16, cB), dim3(256), 0, stream, h, ws,
                       ws + OFF_PC, ws + OFF_PS);
    hipLaunchKernelGGL(k_reduce, dim3(512), dim3(256), 0, stream,
                       ws + OFF_PC, ws + OFF_PS, ws + OFF_XC, ws + OFF_XS);
    hipLaunchKernelGGL(k_lowrank, dim3(cB), dim3(cK), 0, stream, ws + OFF_XC,
                       ws + OFF_XS, wc1, wc2, ws1, ws2, w01, w02,
                       ws + OFF_FCT, ws + OFF_FST, ws + OFF_F0, l);
    hipLaunchKernelGGL(k_inverse, dim3(cN / 128, cB), dim3(256), 0, stream, h, ws,
                       wconv, bconv, l, (l != cNL - 1) ? 1 : 0);
  }
  hipLaunchKernelGGL(k_final, dim3(cN / 64, cB), dim3(256), 0, stream, h, fc1_w,
                     fc1_b, fc2_w, fc2_b, out);
}

// Round 4
// 838.505 us; speedup vs baseline: 4.1235x; 1.0395x over previous
//
#include <hip/hip_runtime.h>
#include <math.h>

namespace {
constexpr int cB = 16, cN = 8192, cC = 64, cK = 128, cR = 4, cNL = 4;
constexpr float kTwoPi = 6.28318530717958647692f;

// workspace layout (float offsets)
constexpr size_t OFF_H     = 0;                                // 8,388,608
constexpr size_t OFF_PACKA = (size_t)cB * cC * cN;             // +524,288
constexpr size_t OFF_PACKB = OFF_PACKA + (size_t)cB * cN * 4;  // +524,288
constexpr size_t OFF_PACKC = OFF_PACKB + (size_t)cB * cN * 4;  // +262,144
constexpr size_t OFF_PC    = OFF_PACKC + (size_t)cB * cN * 2;  // 512 slots * 8192
constexpr size_t OFF_PS    = OFF_PC + (size_t)512 * 8192;
constexpr size_t OFF_XC    = OFF_PS + (size_t)512 * 8192;
constexpr size_t OFF_XS    = OFF_XC + (size_t)cB * cC * cK;
constexpr size_t OFF_FCT   = OFF_XS + (size_t)cB * cC * cK;
constexpr size_t OFF_FST   = OFF_FCT + (size_t)cB * cK * cC;
constexpr size_t OFF_F0    = OFF_FST + (size_t)cB * cK * cC;
// end = 18,613,248 floats = 74.5 MB

__device__ __forceinline__ float gelu_f(float x) {
  return 0.5f * x * (1.0f + erff(x * 0.7071067811865475244f));
}

struct cpx { float x, y; };
__device__ __forceinline__ cpx cmul(cpx a, cpx b) {
  cpx r;
  r.x = fmaf(a.x, b.x, -(a.y * b.y));
  r.y = fmaf(a.x, b.y, a.y * b.x);
  return r;
}

// thread g (0..7) produces modes k = 8g+ky and 64+8g+ky (ky=0..7) for one point.
__device__ __forceinline__ void compute_modes(int g, float4 pA, float4 pB,
                                              float* cw_row, float* sw_row) {
  cpx ex{pA.x, pA.y}, ey{pA.z, pA.w}, ex8{pB.x, pB.y}, ey4{pB.z, pB.w};
  cpx eyp[8];
  eyp[0] = {1.0f, 0.0f};
  eyp[1] = ey;
  eyp[2] = cmul(ey, ey);
  eyp[3] = cmul(eyp[2], ey);
  eyp[4] = ey4;
  eyp[5] = cmul(ey4, ey);
  eyp[6] = cmul(ey4, eyp[2]);
  eyp[7] = cmul(ey4, eyp[3]);
  cpx r{1.0f, 0.0f};
  cpx t = ex;
  if (g & 1) r = t;
  t = cmul(t, t);
  if (g & 2) r = cmul(r, t);
  t = cmul(t, t);
  if (g & 4) r = cmul(r, t);
  cpx r8 = cmul(r, ex8);
  float mc[8], msn[8], mc2[8], msn2[8];
#pragma unroll
  for (int ky = 0; ky < 8; ky++) {
    cpx m1 = cmul(r, eyp[ky]);
    cpx m2 = cmul(r8, eyp[ky]);
    mc[ky] = m1.x; msn[ky] = m1.y;
    mc2[ky] = m2.x; msn2[ky] = m2.y;
  }
  *(float4*)&cw_row[8 * g]          = make_float4(mc[0], mc[1], mc[2], mc[3]);
  *(float4*)&cw_row[8 * g + 4]      = make_float4(mc[4], mc[5], mc[6], mc[7]);
  *(float4*)&cw_row[64 + 8 * g]     = make_float4(mc2[0], mc2[1], mc2[2], mc2[3]);
  *(float4*)&cw_row[64 + 8 * g + 4] = make_float4(mc2[4], mc2[5], mc2[6], mc2[7]);
  *(float4*)&sw_row[8 * g]          = make_float4(msn[0], msn[1], msn[2], msn[3]);
  *(float4*)&sw_row[8 * g + 4]      = make_float4(msn[4], msn[5], msn[6], msn[7]);
  *(float4*)&sw_row[64 + 8 * g]     = make_float4(msn2[0], msn2[1], msn2[2], msn2[3]);
  *(float4*)&sw_row[64 + 8 * g + 4] = make_float4(msn2[4], msn2[5], msn2[6], msn2[7]);
}
}  // namespace

// --- prep: fc0 into (B,C,N), per-point phase factors
__global__ void __launch_bounds__(256) k_prep(const float* __restrict__ x,
                                              const float* __restrict__ fc0_w,
                                              const float* __restrict__ fc0_b,
                                              float* __restrict__ ws) {
  int t = blockIdx.x * 256 + threadIdx.x;
  int b = t >> 13;
  int n = t & (cN - 1);
  const float* xp = x + (size_t)t * 7;
  float f0 = xp[0], f1 = xp[1], f2 = xp[2];
  float gx = xp[3], gy = xp[4], w = xp[5], m = xp[6];
  float ax = kTwoPi * gx, ay = kTwoPi * gy;
  float sx, cx, sy, cy, s8x, c8x, s4y, c4y;
  sincosf(ax, &sx, &cx);
  sincosf(ay, &sy, &cy);
  sincosf(8.0f * ax, &s8x, &c8x);
  sincosf(4.0f * ay, &s4y, &c4y);
  ((float4*)(ws + OFF_PACKA))[t] = make_float4(cx, sx, cy, sy);
  ((float4*)(ws + OFF_PACKB))[t] = make_float4(c8x, s8x, c4y, s4y);
  ((float2*)(ws + OFF_PACKC))[t] = make_float2(w * (float)cN * m, m);
  float* h = ws + OFF_H + (size_t)b * cC * cN + n;
#pragma unroll
  for (int c = 0; c < cC; c++) {
    float v = fc0_b[c] + f0 * fc0_w[c] + f1 * fc0_w[cC + c] + f2 * fc0_w[2 * cC + c];
    h[(size_t)c * cN] = v;
  }
}

// --- forward: per-block partial Xc/Xs (64c x 128k), 512 blocks, no atomics
__global__ void __launch_bounds__(256) k_forward(const float* __restrict__ hg,
                                                 const float* __restrict__ ws,
                                                 float* __restrict__ Pc,
                                                 float* __restrict__ Ps) {
  __shared__ __align__(16) float hs[32 * 68];   // [s][c], pad 68
  __shared__ __align__(16) float cw[32 * 132];  // [s][k]
  __shared__ __align__(16) float sw[32 * 132];
  int b = blockIdx.y, nb = blockIdx.x;  // nb 0..31
  int n_base = nb * 256;
  int tid = threadIdx.x;
  int g = tid >> 5, nn = tid & 31;   // staging/basis mapping
  int tc = tid >> 5, tkq = tid & 31; // compute: c0=tc*8, k=4tkq+q
  const float4* pA = (const float4*)(ws + OFF_PACKA) + (size_t)b * cN;
  const float4* pB = (const float4*)(ws + OFF_PACKB) + (size_t)b * cN;
  const float2* pC = (const float2*)(ws + OFF_PACKC) + (size_t)b * cN;
  const float* hb = hg + (size_t)b * cC * cN;
  float accC[8][4] = {}, accS[8][4] = {};
  // prefetch tile 0
  float4 a4 = pA[n_base + nn];
  float4 b4 = pB[n_base + nn];
  float2 c2 = pC[n_base + nn];
  float hv8[8];
#pragma unroll
  for (int i = 0; i < 8; i++) hv8[i] = hb[(size_t)(g + 8 * i) * cN + n_base + nn];
  for (int tile = 0; tile < 8; tile++) {
    __syncthreads();
#pragma unroll
    for (int i = 0; i < 8; i++) hs[nn * 68 + g + 8 * i] = hv8[i] * c2.x;
    compute_modes(g, a4, b4, &cw[nn * 132], &sw[nn * 132]);
    if (tile < 7) {  // software-pipelined prefetch of next tile
      int n0 = n_base + (tile + 1) * 32;
      a4 = pA[n0 + nn];
      b4 = pB[n0 + nn];
      c2 = pC[n0 + nn];
#pragma unroll
      for (int i = 0; i < 8; i++) hv8[i] = hb[(size_t)(g + 8 * i) * cN + n0 + nn];
    }
    __syncthreads();
#pragma unroll 2
    for (int s = 0; s < 32; s++) {
      float4 h0 = *(const float4*)&hs[s * 68 + tc * 8];
      float4 h1 = *(const float4*)&hs[s * 68 + tc * 8 + 4];
      float4 c4v = *(const float4*)&cw[s * 132 + tkq * 4];
      float4 s4v = *(const float4*)&sw[s * 132 + tkq * 4];
      float hj[8] = {h0.x, h0.y, h0.z, h0.w, h1.x, h1.y, h1.z, h1.w};
      float cc[4] = {c4v.x, c4v.y, c4v.z, c4v.w};
      float ss[4] = {s4v.x, s4v.y, s4v.z, s4v.w};
#pragma unroll
      for (int j = 0; j < 8; j++)
#pragma unroll
        for (int q = 0; q < 4; q++) {
          accC[j][q] = fmaf(hj[j], cc[q], accC[j][q]);
          accS[j][q] = fmaf(hj[j], ss[q], accS[j][q]);
        }
    }
  }
  float* pcb = Pc + (size_t)(b * 32 + nb) * 8192;
  float* psb = Ps + (size_t)(b * 32 + nb) * 8192;
#pragma unroll
  for (int j = 0; j < 8; j++) {
    int off = (tc * 8 + j) * 128 + tkq * 4;
    *(float4*)&pcb[off] = make_float4(accC[j][0], accC[j][1], accC[j][2], accC[j][3]);
    *(float4*)&psb[off] = make_float4(accS[j][0], accS[j][1], accS[j][2], accS[j][3]);
  }
}

// --- reduce 32 partials -> Xc/Xs
__global__ void __launch_bounds__(256) k_reduce(const float* __restrict__ Pc,
                                                const float* __restrict__ Ps,
                                                float* __restrict__ Xc,
                                                float* __restrict__ Xs) {
  int idx = blockIdx.x * 256 + threadIdx.x;  // 0..131071
  int b = idx >> 13;
  int rest = idx & 8191;
  float sc = 0.0f, ss = 0.0f;
#pragma unroll
  for (int nb = 0; nb < 32; nb++) {
    sc += Pc[(size_t)(b * 32 + nb) * 8192 + rest];
    ss += Ps[(size_t)(b * 32 + nb) * 8192 + rest];
  }
  Xc[idx] = sc;
  Xs[idx] = ss;
}

// --- low-rank mixing; grid (16b, 4kq) x 32 threads; X0 = Xc[:, :, 0]
__global__ void k_lowrank(const float* __restrict__ Xc, const float* __restrict__ Xs,
                          const float* __restrict__ wc1, const float* __restrict__ wc2,
                          const float* __restrict__ ws1, const float* __restrict__ ws2,
                          const float* __restrict__ w01, const float* __restrict__ w02,
                          float* __restrict__ FcT, float* __restrict__ FsT,
                          float* __restrict__ F0, int layer) {
  int b = blockIdx.x;
  int k = blockIdx.y * 32 + threadIdx.x;
  const float* xcb = Xc + (size_t)b * cC * cK;
  const float* xsb = Xs + (size_t)b * cC * cK;
  if (blockIdx.y == 0 && threadIdx.x == 0) {
    float t[cR] = {};
    for (int i = 0; i < cC; i++) {
      float xv = xcb[(size_t)i * cK];
#pragma unroll
      for (int r = 0; r < cR; r++) t[r] += xv * w01[((size_t)layer * cC + i) * cR + r];
    }
    for (int o = 0; o < cC; o++) {
      float f = 0.0f;
#pragma unroll
      for (int r = 0; r < cR; r++) f += t[r] * w02[((size_t)layer * cR + r) * cC + o];
      F0[b * cC + o] = f / (float)cN;
    }
  }
  const float* c1 = wc1 + (size_t)layer * cC * cR * cK;
  const float* s1 = ws1 + (size_t)layer * cC * cR * cK;
  const float* c2 = wc2 + (size_t)layer * cR * cC * cK;
  const float* s2 = ws2 + (size_t)layer * cR * cC * cK;
  float A1[cR] = {}, A2[cR] = {}, B1[cR] = {}, B2[cR] = {};
  for (int i = 0; i < cC; i++) {
    size_t idx = (size_t)i * cK + k;
    float xcv = xcb[idx];
    float xsv = -xsb[idx];  // x_s = -sum(h*a*sin)
#pragma unroll
    for (int r = 0; r < cR; r++) {
      float w1c = c1[((size_t)i * cR + r) * cK + k];
      float w1sv = s1[((size_t)i * cR + r) * cK + k];
      A1[r] += xcv * w1c;
      A2[r] += xcv * w1sv;
      B1[r] += xsv * w1c;
      B2[r] += xsv * w1sv;
    }
  }
  const float scale = 2.0f / (float)cN;
  float* fct = FcT + ((size_t)b * cK + k) * cC;
  float* fst = FsT + ((size_t)b * cK + k) * cC;
  for (int o = 0; o < cC; o++) {
    float fc = 0.0f, fs = 0.0f;
#pragma unroll
    for (int r = 0; r < cR; r++) {
      float w2c = c2[((size_t)r * cC + o) * cK + k];
      float w2s = s2[((size_t)r * cC + o) * cK + k];
      fc += A1[r] * w2c - B2[r] * w2s;
      fs += B1[r] * w2c + A2[r] * w2s;
    }
    fct[o] = scale * fc;
    fst[o] = scale * fs;
  }
}

// --- inverse transform + conv + bias + gelu; 256 pts/block, 8n x 8c tiles
__global__ void __launch_bounds__(256, 3) k_inverse(float* __restrict__ h,
                                                    const float* __restrict__ ws,
                                                    const float* __restrict__ wconv,
                                                    const float* __restrict__ bconv,
                                                    int layer, int do_gelu) {
  __shared__ __align__(16) float bc[16 * 256];  // [kl][n]; reused for wconv in conv phase
  __shared__ __align__(16) float bs[16 * 256];
  __shared__ __align__(16) float fcs[16 * 64];  // [kl][c]
  __shared__ __align__(16) float fss[16 * 64];
  __shared__ float msk[256];
  int b = blockIdx.y;
  int n_blk = blockIdx.x * 256;
  int tid = threadIdx.x;
  int tn = tid & 31, tc = tid >> 5;
  int n0l = tn * 8, c0 = tc * 8;
  const float4* pA = (const float4*)(ws + OFF_PACKA) + (size_t)b * cN;
  const float4* pB = (const float4*)(ws + OFF_PACKB) + (size_t)b * cN;
  const float2* pC = (const float2*)(ws + OFF_PACKC) + (size_t)b * cN;
  // per-point phase anchors (p = tid)
  float4 a4 = pA[n_blk + tid];
  float4 b4 = pB[n_blk + tid];
  msk[tid] = pC[n_blk + tid].y;
  cpx ex{a4.x, a4.y}, ey{a4.z, a4.w}, ex8{b4.x, b4.y}, ey4{b4.z, b4.w};
  cpx ex2 = cmul(ex, ex);
  cpx ex4 = cmul(ex2, ex2);
  cpx ex12 = cmul(ex8, ex4);
  cpx eyp[8];
  eyp[0] = {1.0f, 0.0f};
  eyp[1] = ey;
  eyp[2] = cmul(ey, ey);
  eyp[3] = cmul(eyp[2], ey);
  eyp[4] = ey4;
  eyp[5] = cmul(ey4, ey);
  eyp[6] = cmul(ey4, eyp[2]);
  eyp[7] = cmul(ey4, eyp[3]);
  const float* FcB = ws + OFF_FCT + (size_t)b * cK * cC;
  const float* FsB = ws + OFF_FST + (size_t)b * cK * cC;
  float4 pf0 = *(const float4*)&FcB[tid * 4];
  float4 pf1 = *(const float4*)&FsB[tid * 4];
  float acc[8][8] = {};
  for (int cc = 0; cc < 8; cc++) {
    __syncthreads();  // previous chunk consumed
    *(float4*)&fcs[tid * 4] = pf0;
    *(float4*)&fss[tid * 4] = pf1;
    // bases for kx = 2cc (kl 0..7) and 2cc+1 (kl 8..15); depth<=3 from exact anchors
    cpx ra;
    switch (cc) {
      case 0: ra = {1.0f, 0.0f}; break;
      case 1: ra = ex2; break;
      case 2: ra = ex4; break;
      case 3: ra = cmul(ex4, ex2); break;
      case 4: ra = ex8; break;
      case 5: ra = cmul(ex8, ex2); break;
      case 6: ra = ex12; break;
      default: ra = cmul(ex12, ex2); break;
    }
    cpx rb = cmul(ra, ex);
#pragma unroll
    for (int ky = 0; ky < 8; ky++) {
      cpx ma = cmul(ra, eyp[ky]);
      cpx mb = cmul(rb, eyp[ky]);
      bc[ky * 256 + tid] = ma.x;
      bs[ky * 256 + tid] = ma.y;
      bc[(8 + ky) * 256 + tid] = mb.x;
      bs[(8 + ky) * 256 + tid] = mb.y;
    }
    if (cc < 7) {
      int off = (cc + 1) * 1024;
      pf0 = *(const float4*)&FcB[off + tid * 4];
      pf1 = *(const float4*)&FsB[off + tid * 4];
    }
    __syncthreads();
#pragma unroll 2
    for (int kk = 0; kk < 16; kk++) {
      float4 b0 = *(const float4*)&bc[kk * 256 + n0l];
      float4 b1 = *(const float4*)&bc[kk * 256 + n0l + 4];
      float4 s0 = *(const float4*)&bs[kk * 256 + n0l];
      float4 s1 = *(const float4*)&bs[kk * 256 + n0l + 4];
      float4 f0 = *(const float4*)&fcs[kk * 64 + c0];
      float4 f1 = *(const float4*)&fcs[kk * 64 + c0 + 4];
      float4 g0 = *(const float4*)&fss[kk * 64 + c0];
      float4 g1 = *(const float4*)&fss[kk * 64 + c0 + 4];
      float bn[8] = {b0.x, b0.y, b0.z, b0.w, b1.x, b1.y, b1.z, b1.w};
      float sn2[8] = {s0.x, s0.y, s0.z, s0.w, s1.x, s1.y, s1.z, s1.w};
      float fcv[8] = {f0.x, f0.y, f0.z, f0.w, f1.x, f1.y, f1.z, f1.w};
      float fsv[8] = {g0.x, g0.y, g0.z, g0.w, g1.x, g1.y, g1.z, g1.w};
#pragma unroll
      for (int nq = 0; nq < 8; nq++)
#pragma unroll
        for (int j = 0; j < 8; j++)
          acc[nq][j] = fmaf(bn[nq], fcv[j], fmaf(-sn2[nq], fsv[j], acc[nq][j]));
    }
  }
  // (F0 + acc) * mask
  const float* F0B = ws + OFF_F0 + (size_t)b * cC;
  float4 fz0 = *(const float4*)&F0B[c0];
  float4 fz1 = *(const float4*)&F0B[c0 + 4];
  float f0v[8] = {fz0.x, fz0.y, fz0.z, fz0.w, fz1.x, fz1.y, fz1.z, fz1.w};
  float4 m0 = *(const float4*)&msk[n0l];
  float4 m1 = *(const float4*)&msk[n0l + 4];
  float mv[8] = {m0.x, m0.y, m0.z, m0.w, m1.x, m1.y, m1.z, m1.w};
#pragma unroll
  for (int nq = 0; nq < 8; nq++)
#pragma unroll
    for (int j = 0; j < 8; j++) acc[nq][j] = (f0v[j] + acc[nq][j]) * mv[nq];
  // stage wconv into bc (reuse), then conv from global h
  const float* wcl = wconv + (size_t)layer * 4096;
  __syncthreads();
#pragma unroll
  for (int i = 0; i < 4; i++)
    *(float4*)&bc[i * 1024 + tid * 4] = *(const float4*)&wcl[i * 1024 + tid * 4];
  __syncthreads();
  float* hb = h + (size_t)b * cC * cN + n_blk;
  for (int i = 0; i < cC; i++) {
    float4 hv0 = *(const float4*)&hb[(size_t)i * cN + n0l];
    float4 hv1 = *(const float4*)&hb[(size_t)i * cN + n0l + 4];
    float4 w0 = *(const float4*)&bc[i * 64 + c0];
    float4 w1 = *(const float4*)&bc[i * 64 + c0 + 4];
    float hn[8] = {hv0.x, hv0.y, hv0.z, hv0.w, hv1.x, hv1.y, hv1.z, hv1.w};
    float wv[8] = {w0.x, w0.y, w0.z, w0.w, w1.x, w1.y, w1.z, w1.w};
#pragma unroll
    for (int nq = 0; nq < 8; nq++)
#pragma unroll
      for (int j = 0; j < 8; j++) acc[nq][j] = fmaf(hn[nq], wv[j], acc[nq][j]);
  }
  __syncthreads();  // all conv reads of h drained before in-place stores
#pragma unroll
  for (int j = 0; j < 8; j++) {
    int c = c0 + j;
    float bv = bconv[layer * cC + c];
    float v[8];
#pragma unroll
    for (int nq = 0; nq < 8; nq++) {
      v[nq] = acc[nq][j] + bv;
      if (do_gelu) v[nq] = gelu_f(v[nq]);
    }
    *(float4*)&hb[(size_t)c * cN + n0l] = make_float4(v[0], v[1], v[2], v[3]);
    *(float4*)&hb[(size_t)c * cN + n0l + 4] = make_float4(v[4], v[5], v[6], v[7]);
  }
}

// --- final MLP: gelu(h^T @ fc1 + b1) @ fc2 + b2
__global__ void __launch_bounds__(256) k_final(const float* __restrict__ h,
                                               const float* __restrict__ fc1_w,
                                               const float* __restrict__ fc1_b,
                                               const float* __restrict__ fc2_w,
                                               const float* __restrict__ fc2_b,
                                               float* __restrict__ out) {
  int b = blockIdx.y;
  int n0 = blockIdx.x * 64;
  int tid = threadIdx.x;
  int tn = tid & 63;
  int tg = tid >> 6;
  __shared__ __align__(16) float w1s[cC * 128];
  __shared__ __align__(16) float hT[cC * 64];
  __shared__ float red[4 * 64];
  const float* hb = h + (size_t)b * cC * cN;
#pragma unroll
  for (int i = 0; i < 16; i++) {
    int e = tid + i * 256;
    int c = e >> 6, nnx = e & 63;
    hT[c * 64 + nnx] = hb[(size_t)c * cN + n0 + nnx];
  }
#pragma unroll
  for (int i = 0; i < 32; i++) {
    int e = tid + i * 256;
    w1s[e] = fc1_w[e];
  }
  __syncthreads();
  int j0 = tg * 32;
  float acc[32] = {};
  for (int c = 0; c < cC; c++) {
    float hv = hT[c * 64 + tn];
#pragma unroll
    for (int jj = 0; jj < 32; jj += 4) {
      float4 w4 = *(const float4*)&w1s[c * 128 + j0 + jj];
      acc[jj] += hv * w4.x;
      acc[jj + 1] += hv * w4.y;
      acc[jj + 2] += hv * w4.z;
      acc[jj + 3] += hv * w4.w;
    }
  }
  float s = 0.0f;
#pragma unroll
  for (int jj = 0; jj < 32; jj++) {
    int j = j0 + jj;
    float v = gelu_f(acc[jj] + fc1_b[j]);
    s += v * fc2_w[j];
  }
  red[tg * 64 + tn] = s;
  __syncthreads();
  if (tg == 0) {
    float r = red[tn] + red[64 + tn] + red[128 + tn] + red[192 + tn] + fc2_b[0];
    out[(size_t)b * cN + n0 + tn] = r;
  }
}

extern "C" void kernel_launch(void* const* d_in, const int* in_sizes, int n_in,
                              void* d_out, int out_size, void* d_ws, size_t ws_size,
                              hipStream_t stream) {
  const float* x = (const float*)d_in[0];
  const float* fc0_w = (const float*)d_in[1];
  const float* fc0_b = (const float*)d_in[2];
  const float* wc1 = (const float*)d_in[3];
  const float* wc2 = (const float*)d_in[4];
  const float* ws1 = (const float*)d_in[5];
  const float* ws2 = (const float*)d_in[6];
  const float* w01 = (const float*)d_in[7];
  const float* w02 = (const float*)d_in[8];
  const float* wconv = (const float*)d_in[9];
  const float* bconv = (const float*)d_in[10];
  const float* fc1_w = (const float*)d_in[11];
  const float* fc1_b = (const float*)d_in[12];
  const float* fc2_w = (const float*)d_in[13];
  const float* fc2_b = (const float*)d_in[14];
  float* ws = (float*)d_ws;
  float* out = (float*)d_out;
  float* h = ws + OFF_H;

  hipLaunchKernelGGL(k_prep, dim3(cB * cN / 256), dim3(256), 0, stream, x, fc0_w, fc0_b, ws);
  for (int l = 0; l < cNL; l++) {
    hipLaunchKernelGGL(k_forward, dim3(32, cB), dim3(256), 0, stream, h, ws,
                       ws + OFF_PC, ws + OFF_PS);
    hipLaunchKernelGGL(k_reduce, dim3(512), dim3(256), 0, stream,
                       ws + OFF_PC, ws + OFF_PS, ws + OFF_XC, ws + OFF_XS);
    hipLaunchKernelGGL(k_lowrank, dim3(cB, 4), dim3(32), 0, stream, ws + OFF_XC,
                       ws + OFF_XS, wc1, wc2, ws1, ws2, w01, w02,
                       ws + OFF_FCT, ws + OFF_FST, ws + OFF_F0, l);
    hipLaunchKernelGGL(k_inverse, dim3(cN / 256, cB), dim3(256), 0, stream, h, ws,
                       wconv, bconv, l, (l != cNL - 1) ? 1 : 0);
  }
  hipLaunchKernelGGL(k_final, dim3(cN / 64, cB), dim3(256), 0, stream, h, fc1_w,
                     fc1_b, fc2_w, fc2_b, out);
}

// Round 5
// 761.237 us; speedup vs baseline: 4.5421x; 1.1015x over previous
//
#include <hip/hip_runtime.h>
#include <math.h>

namespace {
constexpr int cB = 16, cN = 8192, cC = 64, cK = 128, cR = 4, cNL = 4;
constexpr float kTwoPi = 6.28318530717958647692f;

// workspace layout (float offsets)
constexpr size_t OFF_H     = 0;                                // 8,388,608
constexpr size_t OFF_PACKA = (size_t)cB * cC * cN;             // +524,288
constexpr size_t OFF_PACKB = OFF_PACKA + (size_t)cB * cN * 4;  // +524,288
constexpr size_t OFF_PACKC = OFF_PACKB + (size_t)cB * cN * 4;  // +262,144
constexpr size_t OFF_PC    = OFF_PACKC + (size_t)cB * cN * 2;  // 512 slots * 8192
constexpr size_t OFF_PS    = OFF_PC + (size_t)512 * 8192;
constexpr size_t OFF_XC    = OFF_PS + (size_t)512 * 8192;
constexpr size_t OFF_XS    = OFF_XC + (size_t)cB * cC * cK;
constexpr size_t OFF_FCT   = OFF_XS + (size_t)cB * cC * cK;
constexpr size_t OFF_FST   = OFF_FCT + (size_t)cB * cK * cC;
constexpr size_t OFF_F0    = OFF_FST + (size_t)cB * cK * cC;
// end = 18,613,248 floats = 74.5 MB

__device__ __forceinline__ float gelu_f(float x) {
  return 0.5f * x * (1.0f + erff(x * 0.7071067811865475244f));
}

struct cpx { float x, y; };
__device__ __forceinline__ cpx cmul(cpx a, cpx b) {
  cpx r;
  r.x = fmaf(a.x, b.x, -(a.y * b.y));
  r.y = fmaf(a.x, b.y, a.y * b.x);
  return r;
}

// thread g (0..7) produces modes k = 8g+ky and 64+8g+ky (ky=0..7) for one point.
__device__ __forceinline__ void compute_modes(int g, float4 pA, float4 pB,
                                              float* cw_row, float* sw_row) {
  cpx ex{pA.x, pA.y}, ey{pA.z, pA.w}, ex8{pB.x, pB.y}, ey4{pB.z, pB.w};
  cpx eyp[8];
  eyp[0] = {1.0f, 0.0f};
  eyp[1] = ey;
  eyp[2] = cmul(ey, ey);
  eyp[3] = cmul(eyp[2], ey);
  eyp[4] = ey4;
  eyp[5] = cmul(ey4, ey);
  eyp[6] = cmul(ey4, eyp[2]);
  eyp[7] = cmul(ey4, eyp[3]);
  cpx r{1.0f, 0.0f};
  cpx t = ex;
  if (g & 1) r = t;
  t = cmul(t, t);
  if (g & 2) r = cmul(r, t);
  t = cmul(t, t);
  if (g & 4) r = cmul(r, t);
  cpx r8 = cmul(r, ex8);
  float mc[8], msn[8], mc2[8], msn2[8];
#pragma unroll
  for (int ky = 0; ky < 8; ky++) {
    cpx m1 = cmul(r, eyp[ky]);
    cpx m2 = cmul(r8, eyp[ky]);
    mc[ky] = m1.x; msn[ky] = m1.y;
    mc2[ky] = m2.x; msn2[ky] = m2.y;
  }
  *(float4*)&cw_row[8 * g]          = make_float4(mc[0], mc[1], mc[2], mc[3]);
  *(float4*)&cw_row[8 * g + 4]      = make_float4(mc[4], mc[5], mc[6], mc[7]);
  *(float4*)&cw_row[64 + 8 * g]     = make_float4(mc2[0], mc2[1], mc2[2], mc2[3]);
  *(float4*)&cw_row[64 + 8 * g + 4] = make_float4(mc2[4], mc2[5], mc2[6], mc2[7]);
  *(float4*)&sw_row[8 * g]          = make_float4(msn[0], msn[1], msn[2], msn[3]);
  *(float4*)&sw_row[8 * g + 4]      = make_float4(msn[4], msn[5], msn[6], msn[7]);
  *(float4*)&sw_row[64 + 8 * g]     = make_float4(msn2[0], msn2[1], msn2[2], msn2[3]);
  *(float4*)&sw_row[64 + 8 * g + 4] = make_float4(msn2[4], msn2[5], msn2[6], msn2[7]);
}
}  // namespace

// --- prep: fc0 into (B,C,N), per-point phase factors
__global__ void __launch_bounds__(256) k_prep(const float* __restrict__ x,
                                              const float* __restrict__ fc0_w,
                                              const float* __restrict__ fc0_b,
                                              float* __restrict__ ws) {
  int t = blockIdx.x * 256 + threadIdx.x;
  int b = t >> 13;
  int n = t & (cN - 1);
  const float* xp = x + (size_t)t * 7;
  float f0 = xp[0], f1 = xp[1], f2 = xp[2];
  float gx = xp[3], gy = xp[4], w = xp[5], m = xp[6];
  float ax = kTwoPi * gx, ay = kTwoPi * gy;
  float sx, cx, sy, cy, s8x, c8x, s4y, c4y;
  sincosf(ax, &sx, &cx);
  sincosf(ay, &sy, &cy);
  sincosf(8.0f * ax, &s8x, &c8x);
  sincosf(4.0f * ay, &s4y, &c4y);
  ((float4*)(ws + OFF_PACKA))[t] = make_float4(cx, sx, cy, sy);
  ((float4*)(ws + OFF_PACKB))[t] = make_float4(c8x, s8x, c4y, s4y);
  ((float2*)(ws + OFF_PACKC))[t] = make_float2(w * (float)cN * m, m);
  float* h = ws + OFF_H + (size_t)b * cC * cN + n;
#pragma unroll
  for (int c = 0; c < cC; c++) {
    float v = fc0_b[c] + f0 * fc0_w[c] + f1 * fc0_w[cC + c] + f2 * fc0_w[2 * cC + c];
    h[(size_t)c * cN] = v;
  }
}

// --- forward: per-block partial Xc/Xs (64c x 128k), 512 blocks, no atomics
__global__ void __launch_bounds__(256) k_forward(const float* __restrict__ hg,
                                                 const float* __restrict__ ws,
                                                 float* __restrict__ Pc,
                                                 float* __restrict__ Ps) {
  __shared__ __align__(16) float hs[32 * 68];   // [s][c], pad 68
  __shared__ __align__(16) float cw[32 * 132];  // [s][k]
  __shared__ __align__(16) float sw[32 * 132];
  int b = blockIdx.y, nb = blockIdx.x;  // nb 0..31
  int n_base = nb * 256;
  int tid = threadIdx.x;
  int g = tid >> 5, nn = tid & 31;   // staging/basis mapping
  int tc = tid >> 5, tkq = tid & 31; // compute: c0=tc*8, k=4tkq+q
  const float4* pA = (const float4*)(ws + OFF_PACKA) + (size_t)b * cN;
  const float4* pB = (const float4*)(ws + OFF_PACKB) + (size_t)b * cN;
  const float2* pC = (const float2*)(ws + OFF_PACKC) + (size_t)b * cN;
  const float* hb = hg + (size_t)b * cC * cN;
  float accC[8][4] = {}, accS[8][4] = {};
  // prefetch tile 0
  float4 a4 = pA[n_base + nn];
  float4 b4 = pB[n_base + nn];
  float2 c2 = pC[n_base + nn];
  float hv8[8];
#pragma unroll
  for (int i = 0; i < 8; i++) hv8[i] = hb[(size_t)(g + 8 * i) * cN + n_base + nn];
  for (int tile = 0; tile < 8; tile++) {
    __syncthreads();
#pragma unroll
    for (int i = 0; i < 8; i++) hs[nn * 68 + g + 8 * i] = hv8[i] * c2.x;
    compute_modes(g, a4, b4, &cw[nn * 132], &sw[nn * 132]);
    if (tile < 7) {  // software-pipelined prefetch of next tile
      int n0 = n_base + (tile + 1) * 32;
      a4 = pA[n0 + nn];
      b4 = pB[n0 + nn];
      c2 = pC[n0 + nn];
#pragma unroll
      for (int i = 0; i < 8; i++) hv8[i] = hb[(size_t)(g + 8 * i) * cN + n0 + nn];
    }
    __syncthreads();
#pragma unroll 2
    for (int s = 0; s < 32; s++) {
      float4 h0 = *(const float4*)&hs[s * 68 + tc * 8];
      float4 h1 = *(const float4*)&hs[s * 68 + tc * 8 + 4];
      float4 c4v = *(const float4*)&cw[s * 132 + tkq * 4];
      float4 s4v = *(const float4*)&sw[s * 132 + tkq * 4];
      float hj[8] = {h0.x, h0.y, h0.z, h0.w, h1.x, h1.y, h1.z, h1.w};
      float cc[4] = {c4v.x, c4v.y, c4v.z, c4v.w};
      float ss[4] = {s4v.x, s4v.y, s4v.z, s4v.w};
#pragma unroll
      for (int j = 0; j < 8; j++)
#pragma unroll
        for (int q = 0; q < 4; q++) {
          accC[j][q] = fmaf(hj[j], cc[q], accC[j][q]);
          accS[j][q] = fmaf(hj[j], ss[q], accS[j][q]);
        }
    }
  }
  float* pcb = Pc + (size_t)(b * 32 + nb) * 8192;
  float* psb = Ps + (size_t)(b * 32 + nb) * 8192;
#pragma unroll
  for (int j = 0; j < 8; j++) {
    int off = (tc * 8 + j) * 128 + tkq * 4;
    *(float4*)&pcb[off] = make_float4(accC[j][0], accC[j][1], accC[j][2], accC[j][3]);
    *(float4*)&psb[off] = make_float4(accS[j][0], accS[j][1], accS[j][2], accS[j][3]);
  }
}

// --- reduce 32 partials -> Xc/Xs
__global__ void __launch_bounds__(256) k_reduce(const float* __restrict__ Pc,
                                                const float* __restrict__ Ps,
                                                float* __restrict__ Xc,
                                                float* __restrict__ Xs) {
  int idx = blockIdx.x * 256 + threadIdx.x;  // 0..131071
  int b = idx >> 13;
  int rest = idx & 8191;
  float sc = 0.0f, ss = 0.0f;
#pragma unroll
  for (int nb = 0; nb < 32; nb++) {
    sc += Pc[(size_t)(b * 32 + nb) * 8192 + rest];
    ss += Ps[(size_t)(b * 32 + nb) * 8192 + rest];
  }
  Xc[idx] = sc;
  Xs[idx] = ss;
}

// --- low-rank mixing; one wave per (b,k); butterfly reduction, no LDS
__global__ void __launch_bounds__(64) k_lowrank(const float* __restrict__ Xc,
                                                const float* __restrict__ Xs,
                                                const float* __restrict__ wc1,
                                                const float* __restrict__ wc2,
                                                const float* __restrict__ ws1,
                                                const float* __restrict__ ws2,
                                                const float* __restrict__ w01,
                                                const float* __restrict__ w02,
                                                float* __restrict__ FcT,
                                                float* __restrict__ FsT,
                                                float* __restrict__ F0, int layer) {
  int b = blockIdx.x;
  int k = blockIdx.y;
  int tid = threadIdx.x;  // lane 0..63; phase1: i=tid, phase2: o=tid
  const float* xcb = Xc + (size_t)b * cC * cK;
  const float* xsb = Xs + (size_t)b * cC * cK;
  float xcv = xcb[(size_t)tid * cK + k];
  float xsv = -xsb[(size_t)tid * cK + k];  // x_s = -sum(h*a*sin)
  const float* c1 = wc1 + (size_t)layer * cC * cR * cK + (size_t)tid * cR * cK + k;
  const float* s1 = ws1 + (size_t)layer * cC * cR * cK + (size_t)tid * cR * cK + k;
  float A1[cR], A2[cR], B1[cR], B2[cR];
#pragma unroll
  for (int r = 0; r < cR; r++) {
    float w1c = c1[(size_t)r * cK];
    float w1sv = s1[(size_t)r * cK];
    A1[r] = xcv * w1c;
    A2[r] = xcv * w1sv;
    B1[r] = xsv * w1c;
    B2[r] = xsv * w1sv;
  }
  // butterfly all-reduce across the wave (64 lanes)
#pragma unroll
  for (int r = 0; r < cR; r++) {
#pragma unroll
    for (int off = 32; off > 0; off >>= 1) {
      A1[r] += __shfl_xor(A1[r], off);
      A2[r] += __shfl_xor(A2[r], off);
      B1[r] += __shfl_xor(B1[r], off);
      B2[r] += __shfl_xor(B2[r], off);
    }
  }
  const float scale = 2.0f / (float)cN;
  const float* c2 = wc2 + (size_t)layer * cR * cC * cK;
  const float* s2 = ws2 + (size_t)layer * cR * cC * cK;
  int o = tid;
  float fc = 0.0f, fs = 0.0f;
#pragma unroll
  for (int r = 0; r < cR; r++) {
    float w2c = c2[((size_t)r * cC + o) * cK + k];
    float w2s = s2[((size_t)r * cC + o) * cK + k];
    fc += A1[r] * w2c - B2[r] * w2s;
    fs += B1[r] * w2c + A2[r] * w2s;
  }
  FcT[((size_t)b * cK + k) * cC + o] = scale * fc;
  FsT[((size_t)b * cK + k) * cC + o] = scale * fs;
  if (k == 0) {  // F0 path: x0 = Xc[b,:,0] == this block's xcv
    float t0[cR];
#pragma unroll
    for (int r = 0; r < cR; r++)
      t0[r] = xcv * w01[((size_t)layer * cC + tid) * cR + r];
#pragma unroll
    for (int r = 0; r < cR; r++) {
#pragma unroll
      for (int off = 32; off > 0; off >>= 1) t0[r] += __shfl_xor(t0[r], off);
    }
    float f = 0.0f;
#pragma unroll
    for (int r = 0; r < cR; r++) f += t0[r] * w02[((size_t)layer * cR + r) * cC + o];
    F0[b * cC + o] = f / (float)cN;
  }
}

// --- inverse transform + conv + bias + gelu; 128 pts/block, conflict-free 4n x 8c
__global__ void __launch_bounds__(256, 4) k_inverse(float* __restrict__ h,
                                                    const float* __restrict__ ws,
                                                    const float* __restrict__ wconv,
                                                    const float* __restrict__ bconv,
                                                    int layer, int do_gelu) {
  __shared__ __align__(16) float bc[16 * 128];  // [kl][n]; reused for wconv
  __shared__ __align__(16) float bs[16 * 128];  // [kl][n]; reused for wconv
  __shared__ __align__(16) float fcs[16 * 64];  // [kl][c]
  __shared__ __align__(16) float fss[16 * 64];
  __shared__ float msk[128];
  int b = blockIdx.y;
  int n_blk = blockIdx.x * 128;
  int tid = threadIdx.x;
  int tn = tid & 31, tc = tid >> 5;
  int n0l = tn * 4, c0 = tc * 8;  // lane n-tile stride 4 -> conflict-free b128
  int p = tid >> 1, t = tid & 1;  // 2 threads per point for basis gen
  const float4* pA = (const float4*)(ws + OFF_PACKA) + (size_t)b * cN;
  const float4* pB = (const float4*)(ws + OFF_PACKB) + (size_t)b * cN;
  const float2* pC = (const float2*)(ws + OFF_PACKC) + (size_t)b * cN;
  float4 a4 = pA[n_blk + p];
  float4 b4 = pB[n_blk + p];
  if (t == 0) msk[p] = pC[n_blk + p].y;
  cpx ex{a4.x, a4.y}, ey{a4.z, a4.w}, ex8{b4.x, b4.y}, ey4{b4.z, b4.w};
  cpx ex2 = cmul(ex, ex);
  cpx ex4 = cmul(ex2, ex2);
  cpx ex12 = cmul(ex8, ex4);
  cpx eyp[8];
  eyp[0] = {1.0f, 0.0f};
  eyp[1] = ey;
  eyp[2] = cmul(ey, ey);
  eyp[3] = cmul(eyp[2], ey);
  eyp[4] = ey4;
  eyp[5] = cmul(ey4, ey);
  eyp[6] = cmul(ey4, eyp[2]);
  eyp[7] = cmul(ey4, eyp[3]);
  const float* FcB = ws + OFF_FCT + (size_t)b * cK * cC;
  const float* FsB = ws + OFF_FST + (size_t)b * cK * cC;
  float4 pf0 = *(const float4*)&FcB[tid * 4];
  float4 pf1 = *(const float4*)&FsB[tid * 4];
  float acc[4][8] = {};
  for (int cc = 0; cc < 8; cc++) {
    __syncthreads();  // previous chunk consumed
    *(float4*)&fcs[tid * 4] = pf0;
    *(float4*)&fss[tid * 4] = pf1;
    // bases for kx = 2cc + t, ky = 0..7 -> kl = t*8 + ky
    cpx ra;
    if (cc == 0) ra = cpx{1.0f, 0.0f};
    else if (cc == 1) ra = ex2;
    else if (cc == 2) ra = ex4;
    else if (cc == 3) ra = cmul(ex4, ex2);
    else if (cc == 4) ra = ex8;
    else if (cc == 5) ra = cmul(ex8, ex2);
    else if (cc == 6) ra = ex12;
    else ra = cmul(ex12, ex2);
    cpx ra_odd = cmul(ra, ex);
    if (t) ra = ra_odd;
#pragma unroll
    for (int ky = 0; ky < 8; ky++) {
      cpx m = cmul(ra, eyp[ky]);
      bc[(t * 8 + ky) * 128 + p] = m.x;
      bs[(t * 8 + ky) * 128 + p] = m.y;
    }
    if (cc < 7) {
      int off = (cc + 1) * 1024;
      pf0 = *(const float4*)&FcB[off + tid * 4];
      pf1 = *(const float4*)&FsB[off + tid * 4];
    }
    __syncthreads();
#pragma unroll 2
    for (int kk = 0; kk < 16; kk++) {
      float4 b0 = *(const float4*)&bc[kk * 128 + n0l];
      float4 s0 = *(const float4*)&bs[kk * 128 + n0l];
      float4 f0 = *(const float4*)&fcs[kk * 64 + c0];
      float4 f1 = *(const float4*)&fcs[kk * 64 + c0 + 4];
      float4 g0 = *(const float4*)&fss[kk * 64 + c0];
      float4 g1 = *(const float4*)&fss[kk * 64 + c0 + 4];
      float bn[4] = {b0.x, b0.y, b0.z, b0.w};
      float sn2[4] = {s0.x, s0.y, s0.z, s0.w};
      float fcv[8] = {f0.x, f0.y, f0.z, f0.w, f1.x, f1.y, f1.z, f1.w};
      float fsv[8] = {g0.x, g0.y, g0.z, g0.w, g1.x, g1.y, g1.z, g1.w};
#pragma unroll
      for (int nq = 0; nq < 4; nq++)
#pragma unroll
        for (int j = 0; j < 8; j++)
          acc[nq][j] = fmaf(bn[nq], fcv[j], fmaf(-sn2[nq], fsv[j], acc[nq][j]));
    }
  }
  // (F0 + acc) * mask
  const float* F0B = ws + OFF_F0 + (size_t)b * cC;
  float4 fz0 = *(const float4*)&F0B[c0];
  float4 fz1 = *(const float4*)&F0B[c0 + 4];
  float f0v[8] = {fz0.x, fz0.y, fz0.z, fz0.w, fz1.x, fz1.y, fz1.z, fz1.w};
  float4 m0 = *(const float4*)&msk[n0l];
  float mv[4] = {m0.x, m0.y, m0.z, m0.w};
#pragma unroll
  for (int nq = 0; nq < 4; nq++)
#pragma unroll
    for (int j = 0; j < 8; j++) acc[nq][j] = (f0v[j] + acc[nq][j]) * mv[nq];
  // stage wconv into bc/bs (reuse), then conv from global h
  const float* wcl = wconv + (size_t)layer * 4096;
  __syncthreads();
  {
    float4 w4 = *(const float4*)&wcl[tid * 4];
    float4 w4b = *(const float4*)&wcl[1024 + tid * 4];
    float4 w4c = *(const float4*)&wcl[2048 + tid * 4];
    float4 w4d = *(const float4*)&wcl[3072 + tid * 4];
    *(float4*)&bc[tid * 4] = w4;
    *(float4*)&bc[1024 + tid * 4] = w4b;
    *(float4*)&bs[tid * 4] = w4c;
    *(float4*)&bs[1024 + tid * 4] = w4d;
  }
  __syncthreads();
  float* hb = h + (size_t)b * cC * cN + n_blk;
  for (int i = 0; i < cC; i++) {
    float4 hv0 = *(const float4*)&hb[(size_t)i * cN + n0l];
    const float* wrow = (i < 32) ? &bc[i * 64] : &bs[(i - 32) * 64];
    float4 w0 = *(const float4*)&wrow[c0];
    float4 w1 = *(const float4*)&wrow[c0 + 4];
    float hn[4] = {hv0.x, hv0.y, hv0.z, hv0.w};
    float wv[8] = {w0.x, w0.y, w0.z, w0.w, w1.x, w1.y, w1.z, w1.w};
#pragma unroll
    for (int nq = 0; nq < 4; nq++)
#pragma unroll
      for (int j = 0; j < 8; j++) acc[nq][j] = fmaf(hn[nq], wv[j], acc[nq][j]);
  }
  __syncthreads();  // all conv reads of h drained before in-place stores
#pragma unroll
  for (int j = 0; j < 8; j++) {
    int c = c0 + j;
    float bv = bconv[layer * cC + c];
    float v[4];
#pragma unroll
    for (int nq = 0; nq < 4; nq++) {
      v[nq] = acc[nq][j] + bv;
      if (do_gelu) v[nq] = gelu_f(v[nq]);
    }
    *(float4*)&hb[(size_t)c * cN + n0l] = make_float4(v[0], v[1], v[2], v[3]);
  }
}

// --- final MLP: gelu(h^T @ fc1 + b1) @ fc2 + b2
__global__ void __launch_bounds__(256) k_final(const float* __restrict__ h,
                                               const float* __restrict__ fc1_w,
                                               const float* __restrict__ fc1_b,
                                               const float* __restrict__ fc2_w,
                                               const float* __restrict__ fc2_b,
                                               float* __restrict__ out) {
  int b = blockIdx.y;
  int n0 = blockIdx.x * 64;
  int tid = threadIdx.x;
  int tn = tid & 63;
  int tg = tid >> 6;
  __shared__ __align__(16) float w1s[cC * 128];
  __shared__ __align__(16) float hT[cC * 64];
  __shared__ float red[4 * 64];
  const float* hb = h + (size_t)b * cC * cN;
#pragma unroll
  for (int i = 0; i < 16; i++) {
    int e = tid + i * 256;
    int c = e >> 6, nnx = e & 63;
    hT[c * 64 + nnx] = hb[(size_t)c * cN + n0 + nnx];
  }
#pragma unroll
  for (int i = 0; i < 32; i++) {
    int e = tid + i * 256;
    w1s[e] = fc1_w[e];
  }
  __syncthreads();
  int j0 = tg * 32;
  float acc[32] = {};
  for (int c = 0; c < cC; c++) {
    float hv = hT[c * 64 + tn];
#pragma unroll
    for (int jj = 0; jj < 32; jj += 4) {
      float4 w4 = *(const float4*)&w1s[c * 128 + j0 + jj];
      acc[jj] += hv * w4.x;
      acc[jj + 1] += hv * w4.y;
      acc[jj + 2] += hv * w4.z;
      acc[jj + 3] += hv * w4.w;
    }
  }
  float s = 0.0f;
#pragma unroll
  for (int jj = 0; jj < 32; jj++) {
    int j = j0 + jj;
    float v = gelu_f(acc[jj] + fc1_b[j]);
    s += v * fc2_w[j];
  }
  red[tg * 64 + tn] = s;
  __syncthreads();
  if (tg == 0) {
    float r = red[tn] + red[64 + tn] + red[128 + tn] + red[192 + tn] + fc2_b[0];
    out[(size_t)b * cN + n0 + tn] = r;
  }
}

extern "C" void kernel_launch(void* const* d_in, const int* in_sizes, int n_in,
                              void* d_out, int out_size, void* d_ws, size_t ws_size,
                              hipStream_t stream) {
  const float* x = (const float*)d_in[0];
  const float* fc0_w = (const float*)d_in[1];
  const float* fc0_b = (const float*)d_in[2];
  const float* wc1 = (const float*)d_in[3];
  const float* wc2 = (const float*)d_in[4];
  const float* ws1 = (const float*)d_in[5];
  const float* ws2 = (const float*)d_in[6];
  const float* w01 = (const float*)d_in[7];
  const float* w02 = (const float*)d_in[8];
  const float* wconv = (const float*)d_in[9];
  const float* bconv = (const float*)d_in[10];
  const float* fc1_w = (const float*)d_in[11];
  const float* fc1_b = (const float*)d_in[12];
  const float* fc2_w = (const float*)d_in[13];
  const float* fc2_b = (const float*)d_in[14];
  float* ws = (float*)d_ws;
  float* out = (float*)d_out;
  float* h = ws + OFF_H;

  hipLaunchKernelGGL(k_prep, dim3(cB * cN / 256), dim3(256), 0, stream, x, fc0_w, fc0_b, ws);
  for (int l = 0; l < cNL; l++) {
    hipLaunchKernelGGL(k_forward, dim3(32, cB), dim3(256), 0, stream, h, ws,
                       ws + OFF_PC, ws + OFF_PS);
    hipLaunchKernelGGL(k_reduce, dim3(512), dim3(256), 0, stream,
                       ws + OFF_PC, ws + OFF_PS, ws + OFF_XC, ws + OFF_XS);
    hipLaunchKernelGGL(k_lowrank, dim3(cB, cK), dim3(64), 0, stream, ws + OFF_XC,
                       ws + OFF_XS, wc1, wc2, ws1, ws2, w01, w02,
                       ws + OFF_FCT, ws + OFF_FST, ws + OFF_F0, l);
    hipLaunchKernelGGL(k_inverse, dim3(cN / 128, cB), dim3(256), 0, stream, h, ws,
                       wconv, bconv, l, (l != cNL - 1) ? 1 : 0);
  }
  hipLaunchKernelGGL(k_final, dim3(cN / 64, cB), dim3(256), 0, stream, h, fc1_w,
                     fc1_b, fc2_w, fc2_b, out);
}